// Round 10
// baseline (410.974 us; speedup 1.0000x reference)
//
#include <hip/hip_runtime.h>
#include <hip/hip_bf16.h>
#include <stdint.h>

// encoder_layer: B=32,S=512,D=512,H=8,DK=64,FF=200. bf16 MFMA, fp32 LN stats.
#define B_  32
#define S_  512
#define D_  512
#define H_  8
#define DK_ 64
#define FF_ 200
#define FFP 256                 // FF padded to 256 (zero-fill) -> unguarded GEMMs
#define M_  (B_*S_)             // 16384
#define MSD ((size_t)B_*S_*D_)  // 8388608
#define NQKV 1536

typedef __hip_bfloat16 bf16;
typedef __attribute__((ext_vector_type(8))) short short8;
typedef __attribute__((ext_vector_type(4))) float f32x4;
typedef __attribute__((ext_vector_type(4))) unsigned short us4;

__device__ inline float b2f(bf16 v) { return __bfloat162float(v); }
__device__ inline bf16  f2b(float v){ return __float2bfloat16(v); }
__device__ inline unsigned short f2bu(float v) {
  union { bf16 h; unsigned short u; } cv; cv.h = __float2bfloat16(v); return cv.u;
}
__device__ inline float bu2f(unsigned short u) {
  union { unsigned short u; bf16 h; } cv; cv.u = u; return b2f(cv.h);
}
__device__ __forceinline__ void async16(const bf16* g, bf16* l) {
  __builtin_amdgcn_global_load_lds((const __attribute__((address_space(1))) void*)g,
                                   (__attribute__((address_space(3))) void*)l, 16, 0, 0);
}

// ---------------- dtype detection (flag=1 -> fp32 inputs) + stats zero ----------------
__global__ void detect_kernel(const unsigned short* __restrict__ xu, int* __restrict__ flag,
                              float* __restrict__ stats) {
  __shared__ int mx[256];
  const int tid = threadIdx.x;
  if (tid < 192) stats[tid] = 0.f;
  int m = 0;
  for (int i = tid * 2; i < 8192; i += 512) {
    int e = (xu[i] >> 7) & 0xFF;
    m = m > e ? m : e;
  }
  mx[tid] = m;
  __syncthreads();
  for (int st = 128; st; st >>= 1) {
    if (tid < st) mx[tid] = mx[tid] > mx[tid + st] ? mx[tid] : mx[tid + st];
    __syncthreads();
  }
  if (tid == 0) *flag = (mx[0] >= 0xC0) ? 1 : 0;
}

// ---------------- x convert, 8 elems/thread ----------------
__global__ __launch_bounds__(256) void cvt_x8(const void* __restrict__ in, bf16* __restrict__ out,
                                              const int* __restrict__ flag) {
  const bool f32in = (*flag != 0);
  size_t i = ((size_t)blockIdx.x * 256 + threadIdx.x) * 8;
  const size_t stride = (size_t)gridDim.x * 256 * 8;
  for (; i < MSD; i += stride) {
    if (f32in) {
      const float4 a = ((const float4*)in)[i/4];
      const float4 b = ((const float4*)in)[i/4 + 1];
      uint4 o; unsigned short* po = (unsigned short*)&o;
      po[0]=f2bu(a.x); po[1]=f2bu(a.y); po[2]=f2bu(a.z); po[3]=f2bu(a.w);
      po[4]=f2bu(b.x); po[5]=f2bu(b.y); po[6]=f2bu(b.z); po[7]=f2bu(b.w);
      *(uint4*)((unsigned short*)out + i) = o;
    } else {
      *(uint4*)((unsigned short*)out + i) = *(const uint4*)((const unsigned short*)in + i);
    }
  }
}

// ---------------- merged weight/bias/gamma convert with zero-padding ----------------
struct Seg { const void* src; void* dst; int srcRows, srcK, dstK, total; };
struct Segs { Seg s[16]; unsigned int isbf; };

__global__ __launch_bounds__(256) void cvt_all(Segs sg, const int* __restrict__ flag) {
  const bool f32in = (*flag != 0);
  const int seg = blockIdx.x & 15;
  const Seg sd = sg.s[seg];
  const int stride = (gridDim.x >> 4) * 256;
  const bool nopad = (sd.srcK == sd.dstK);
  for (int i = (blockIdx.x >> 4) * 256 + threadIdx.x; i < sd.total; i += stride) {
    int sidx; bool valid;
    if (nopad) { sidx = i; valid = (i < sd.srcRows * sd.srcK); }
    else {
      int r = i / sd.dstK, c = i - r * sd.dstK;
      valid = (r < sd.srcRows) && (c < sd.srcK);
      sidx = r * sd.srcK + c;
    }
    float v = 0.f;
    if (valid) v = f32in ? ((const float*)sd.src)[sidx] : b2f(((const bf16*)sd.src)[sidx]);
    if (sg.isbf & (1u << seg)) ((unsigned short*)sd.dst)[i] = f2bu(v);
    else                       ((float*)sd.dst)[i] = v;
  }
}

// ---------------- bf16 MFMA GEMM: 3-plane pipeline, SINGLE barrier per K-step --------
// C[m,n] = sum_k A[m,k]*W[n,k] + bias[n].  Requires M%128==0, N%128==0, K%32==0, K>=96.
// MODE: 0=plain, 1=relu, 2=+residual R(bf16)
// STATS: accumulate per-batch sum/sumsq of stored value into stats[b*2(+1)]
// Grid is (M/128, N/128) M-fast: blocks sharing an A-panel land on the SAME XCD.
// R8's proven form (273.6us best). R9's 4-plane variant regressed: occupancy
// 24.5->16.6%, FETCH 29->36MB. Analysis: K-loop is LDS-BW-bound (~96KB LDS traffic
// per CU-iter ~= the 1075cyc period) -> deeper prefetch cannot help at this tile.
template<int MODE, int STATS>
__global__ __launch_bounds__(256) void gemm_mfma(
    const bf16* __restrict__ A, const bf16* __restrict__ W, const float* __restrict__ bias,
    const bf16* __restrict__ R, bf16* __restrict__ C, int M, int N, int K,
    float* __restrict__ stats)
{
  __shared__ __align__(16) char smem[49152];
  bf16*  As  = (bf16*)smem;                 // [3][128][32]  24 KB
  bf16*  Bs  = (bf16*)(smem + 24576);       // [3][128][32]  24 KB
  float* Lf  = (float*)smem;                // [32][132] fp32 epilogue staging (16896 B)
  float* red = (float*)(smem + 16896);      // 512 floats stats reduction

  const int tid  = threadIdx.x;
  const int bm   = blockIdx.x * 128;
  const int bn   = blockIdx.y * 128;
  const int w    = tid >> 6;
  const int lane = tid & 63;
  const int qd   = lane >> 4;
  const int ln   = lane & 15;
  const int wr   = (w >> 1) * 64;
  const int wc   = (w & 1) * 64;

  const int r0 = lane >> 2;
  const int ch = (lane & 3) * 8;
  const bf16* Ag0 = A + (size_t)(bm + w*16 + r0) * K + ch;
  const bf16* Ag1 = Ag0 + (size_t)64 * K;
  const bf16* Bg0 = W + (size_t)(bn + w*16 + r0) * K + ch;
  const bf16* Bg1 = Bg0 + (size_t)64 * K;
  const int lo = w*512 + lane*8;            // offset within a 4096-elem plane

  f32x4 acc[4][4] = {};
  const int nt = K >> 5;

  // prologue: stage tiles 0,1 into planes 0,1
  async16(Ag0, As + lo);
  async16(Ag1, As + lo + 2048);
  async16(Bg0, Bs + lo);
  async16(Bg1, Bs + lo + 2048);
  async16(Ag0 + 32, As + 4096 + lo);
  async16(Ag1 + 32, As + 4096 + lo + 2048);
  async16(Bg0 + 32, Bs + 4096 + lo);
  async16(Bg1 + 32, Bs + 4096 + lo + 2048);

  int pcur = 0;                              // plane holding tile t
  for (int t = 0; t < nt; t++) {
    if (t + 1 < nt) {
      asm volatile("s_waitcnt vmcnt(4)" ::: "memory");   // tile-t landed; t+1 in flight
    } else {
      asm volatile("s_waitcnt vmcnt(0)" ::: "memory");
    }
    __builtin_amdgcn_s_barrier();                        // tile t visible to all waves

    const int cur = pcur << 12;
    short8 af[4], bfr[4];
#pragma unroll
    for (int i = 0; i < 4; i++) af[i]  = *(const short8*)(As + cur + (wr + i*16 + ln)*32 + qd*8);
#pragma unroll
    for (int j = 0; j < 4; j++) bfr[j] = *(const short8*)(Bs + cur + (wc + j*16 + ln)*32 + qd*8);

    if (t + 2 < nt) {
      int pst = pcur - 1; if (pst < 0) pst = 2;   // (pcur+2)%3
      const int nxt = pst << 12;
      const int k0  = (t + 2) << 5;
      async16(Ag0 + k0, As + nxt + lo);
      async16(Ag1 + k0, As + nxt + lo + 2048);
      async16(Bg0 + k0, Bs + nxt + lo);
      async16(Bg1 + k0, Bs + nxt + lo + 2048);
    }

#pragma unroll
    for (int i = 0; i < 4; i++)
#pragma unroll
      for (int j = 0; j < 4; j++)
        acc[i][j] = __builtin_amdgcn_mfma_f32_16x16x32_bf16(af[i], bfr[j], acc[i][j], 0, 0, 0);

    pcur = pcur + 1 == 3 ? 0 : pcur + 1;
  }
  __syncthreads();                           // all reads done before Lf aliases planes

  // ---- epilogue: 4 chunks of 32 rows; stage fp32 in LDS, readback coalesced ----
  float s_acc = 0.f, ss_acc = 0.f;
  const int lrbase = (w >> 1)*16 + qd*4;
#pragma unroll
  for (int i = 0; i < 4; i++) {
#pragma unroll
    for (int j = 0; j < 4; j++) {
      const int col = wc + j*16 + ln;
#pragma unroll
      for (int rg = 0; rg < 4; rg++)
        Lf[(lrbase + rg)*132 + col] = acc[i][j][rg];
    }
    __syncthreads();
    // readback: 2 pairs of float4 per thread -> one 16B bf16 store each
#pragma unroll
    for (int pz = 0; pz < 2; pz++) {
      const int q   = tid + pz*256;
      const int r   = q >> 4;            // 0..31
      const int nof = (q & 15)*8;        // 0..120
      const int m   = bm + (r >> 4)*64 + i*16 + (r & 15);
      const int n   = bn + nof;
      f32x4 v0 = *(const f32x4*)(Lf + r*132 + nof);
      f32x4 v1 = *(const f32x4*)(Lf + r*132 + nof + 4);
      f32x4 b0 = *(const f32x4*)(bias + n);
      f32x4 b1 = *(const f32x4*)(bias + n + 4);
      float vals[8];
#pragma unroll
      for (int e = 0; e < 4; e++) { vals[e] = v0[e] + b0[e]; vals[4+e] = v1[e] + b1[e]; }
      if (MODE == 1) {
#pragma unroll
        for (int e = 0; e < 8; e++) vals[e] = fmaxf(vals[e], 0.f);
      }
      if (MODE == 2) {
        const uint4 rv = *(const uint4*)((const unsigned short*)R + (size_t)m * N + n);
        const unsigned short* rp = (const unsigned short*)&rv;
#pragma unroll
        for (int e = 0; e < 8; e++) vals[e] += bu2f(rp[e]);
      }
      if (STATS) {
#pragma unroll
        for (int e = 0; e < 8; e++) { s_acc += vals[e]; ss_acc += vals[e]*vals[e]; }
      }
      uint4 o; unsigned short* op = (unsigned short*)&o;
#pragma unroll
      for (int e = 0; e < 8; e++) op[e] = f2bu(vals[e]);
      *(uint4*)((unsigned short*)C + (size_t)m * N + n) = o;
    }
    __syncthreads();
  }

  if (STATS) {
    red[tid] = s_acc; red[256 + tid] = ss_acc;
    __syncthreads();
    for (int st = 128; st; st >>= 1) {
      if (tid < st) { red[tid] += red[tid + st]; red[256 + tid] += red[256 + tid + st]; }
      __syncthreads();
    }
    if (tid == 0) {
      const int b = bm >> 9;
      atomicAdd(&stats[b*2],     red[0]);
      atomicAdd(&stats[b*2 + 1], red[256]);
    }
  }
}

// ---------------- attention: 4-chunk K/V staging pipeline (T14, extends R8's 2-chunk) --
// qkv: [M][1536] = [b*512+s][q(512)|k(512)|v(512)], head h at columns h*64.
// One block per (b,h); 16 waves; each wave does 32 queries x 512 keys.
// Keys in 4 chunks of 128. Prologue stages only chunk 0 (1/4 of old serial front).
// After the first sync, ALL of chunks 1-3 are issued (K via async16 direct-to-LDS,
// V into 3 held uint4 regs; issue order K1,V1,K2,V2,K3,V3 -> 6 outstanding/thread).
// Between 4-st compute groups: counted vmcnt(4)/(2)/(0) -> V-reg transpose-write ->
// lgkmcnt(0) -> raw s_barrier (counted waits keep later prefetches alive).
// Outer c-loop is #pragma unroll so vhold[c] stays register-indexed (rule #20).
// Disjoint LDS regions per chunk -> no read/write races.
__global__ __launch_bounds__(1024, 4) void attn_lds(const bf16* __restrict__ qkv,
                                                    bf16* __restrict__ cat)
{
  __shared__ bf16 Ks[2 * 512 * 32];     // 64 KB [ks][key][32]
  __shared__ bf16 Vs[64 * 520];         // 65 KB [dk][key] padded
  __shared__ bf16 pbuf[16][16][40];     // 20 KB per-wave prob staging

  const int tid  = threadIdx.x;
  const int w    = tid >> 6;
  const int lane = tid & 63;
  const int qd   = lane >> 4;
  const int ln   = lane & 15;
  const int bh   = blockIdx.x;
  const int b    = bh >> 3, h = bh & 7;
  const bf16* base = qkv + (size_t)b * 512 * NQKV + h * 64;

  const int kpart = tid & 3;
  const int kkey  = (tid >> 2) & 127;
  const int kks   = tid >> 9;
  const int vdkg  = tid >> 7;
  const int vkey0 = tid & 127;

  // --- chunk 0 (keys 0..127): K async16, V load+transpose-write now ---
  async16(base + (size_t)kkey * NQKV + 512 + kks*32 + kpart*8,
          Ks + kks*16384 + kkey*32 + kpart*8);
  {
    uint4 vv = *(const uint4*)(base + (size_t)vkey0 * NQKV + 1024 + vdkg*8);
    const unsigned short* pv = (const unsigned short*)&vv;
#pragma unroll
    for (int j = 0; j < 8; j++)
      *(unsigned short*)&Vs[(vdkg*8 + j)*520 + vkey0] = pv[j];
  }
  // --- Q B-frags for this wave's 32 queries ---
  short8 bq[2][2];
#pragma unroll
  for (int qt = 0; qt < 2; qt++)
#pragma unroll
    for (int ks = 0; ks < 2; ks++)
      bq[qt][ks] = *(const short8*)(base + (size_t)(w*32 + qt*16 + ln) * NQKV + ks*32 + qd*8);

  __syncthreads();                              // chunk 0 visible (drains everything)

  // --- issue chunks 1..3 in one burst: order K1,V1,K2,V2,K3,V3 ---
  uint4 vhold[3];
#pragma unroll
  for (int c = 1; c < 4; c++) {
    const int key = c*128 + kkey;
    async16(base + (size_t)key * NQKV + 512 + kks*32 + kpart*8,
            Ks + kks*16384 + key*32 + kpart*8);
    vhold[c-1] = *(const uint4*)(base + (size_t)(c*128 + vkey0) * NQKV + 1024 + vdkg*8);
  }
  asm volatile("" ::: "memory");                // pin load issue before compute

  bf16 (*pb)[40] = pbuf[w];
  f32x4 o[2][4] = {};
  float l[2] = {0.f, 0.f};

#pragma unroll
  for (int c = 0; c < 4; c++) {
    for (int st = c*4; st < c*4 + 4; st++) {
      short8 ak[2][2];
#pragma unroll
      for (int kt = 0; kt < 2; kt++)
#pragma unroll
        for (int ks = 0; ks < 2; ks++)
          ak[kt][ks] = *(const short8*)(Ks + ks*16384 + (st*32 + kt*16 + ln)*32 + qd*8);
      f32x4 s[2][2] = {};
#pragma unroll
      for (int kt = 0; kt < 2; kt++)
#pragma unroll
        for (int qt = 0; qt < 2; qt++) {
          s[kt][qt] = __builtin_amdgcn_mfma_f32_16x16x32_bf16(ak[kt][0], bq[qt][0], s[kt][qt], 0, 0, 0);
          s[kt][qt] = __builtin_amdgcn_mfma_f32_16x16x32_bf16(ak[kt][1], bq[qt][1], s[kt][qt], 0, 0, 0);
        }
      float e[2][2][4];
#pragma unroll
      for (int kt = 0; kt < 2; kt++)
#pragma unroll
        for (int qt = 0; qt < 2; qt++)
#pragma unroll
          for (int rg = 0; rg < 4; rg++) {
            float ev = __expf(s[kt][qt][rg] * 0.125f);
            e[kt][qt][rg] = ev;
            l[qt] += ev;
          }
#pragma unroll
      for (int qt = 0; qt < 2; qt++) {
#pragma unroll
        for (int kt = 0; kt < 2; kt++) {
          uint2 pk;
          pk.x = (unsigned)f2bu(e[kt][qt][0]) | ((unsigned)f2bu(e[kt][qt][1]) << 16);
          pk.y = (unsigned)f2bu(e[kt][qt][2]) | ((unsigned)f2bu(e[kt][qt][3]) << 16);
          *(uint2*)&pb[ln][kt*16 + qd*4] = pk;
        }
        short8 ap = *(const short8*)&pb[ln][qd*8];
#pragma unroll
        for (int nt = 0; nt < 4; nt++) {
          short8 bv = *(const short8*)(Vs + (nt*16 + ln)*520 + st*32 + qd*8);
          o[qt][nt] = __builtin_amdgcn_mfma_f32_16x16x32_bf16(ap, bv, o[qt][nt], 0, 0, 0);
        }
      }
    }
    if (c < 3) {
      // land chunk c+1: K(c+1) already in LDS once its vmem retires; V from regs.
      if (c == 0)      asm volatile("s_waitcnt vmcnt(4)" ::: "memory");
      else if (c == 1) asm volatile("s_waitcnt vmcnt(2)" ::: "memory");
      else             asm volatile("s_waitcnt vmcnt(0)" ::: "memory");
      const unsigned short* pv = (const unsigned short*)&vhold[c];
      const int vkey = (c+1)*128 + vkey0;
#pragma unroll
      for (int j = 0; j < 8; j++)
        *(unsigned short*)&Vs[(vdkg*8 + j)*520 + vkey] = pv[j];
      asm volatile("s_waitcnt lgkmcnt(0)" ::: "memory");
      __builtin_amdgcn_s_barrier();             // chunk c+1 visible to all waves
    }
  }

#pragma unroll
  for (int qt = 0; qt < 2; qt++) {
    l[qt] += __shfl_xor(l[qt], 16);
    l[qt] += __shfl_xor(l[qt], 32);
  }
  float inv0 = 1.f / l[0], inv1 = 1.f / l[1];

  const size_t crow0 = (size_t)(b*S_ + w*32) * D_ + h*DK_;
#pragma unroll
  for (int qt = 0; qt < 2; qt++) {
#pragma unroll
    for (int rg = 0; rg < 4; rg++) {
      float ivv = __shfl(qt ? inv1 : inv0, qd*4 + rg);
      int r = qt*16 + qd*4 + rg;
      bf16* cp = cat + crow0 + (size_t)r * D_ + ln;
#pragma unroll
      for (int nt = 0; nt < 4; nt++) cp[nt*16] = f2b(o[qt][nt][rg] * ivv);
    }
  }
}

// ---------------- LN applies (bf16 in), stats precomputed, bf16 gamma/beta ----------------
__global__ __launch_bounds__(256) void ln_b16_b16(const bf16* __restrict__ in,
    const float* __restrict__ stats, const bf16* __restrict__ gamma,
    const bf16* __restrict__ beta, bf16* __restrict__ out)
{
  const int b = blockIdx.x >> 4;
  const float invN = 1.f / (float)(S_*D_);
  const float m    = stats[b*2] * invN;
  const float var  = stats[b*2+1] * invN - m*m;
  const float rstd = rsqrtf(var + 1e-5f);
  size_t v = (size_t)b * 65536 + (blockIdx.x & 15) * 4096 + threadIdx.x;
#pragma unroll 4
  for (int it = 0; it < 16; it++, v += 256) {
    us4 xi = *(const us4*)((const unsigned short*)in + v*4);
    size_t e = (v * 4) & (S_*D_ - 1);
    us4 g4 = *(const us4*)((const unsigned short*)gamma + e);
    us4 b4 = *(const us4*)((const unsigned short*)beta + e);
    us4 o;
    o[0] = f2bu((bu2f(xi[0]) - m) * rstd * bu2f(g4[0]) + bu2f(b4[0]));
    o[1] = f2bu((bu2f(xi[1]) - m) * rstd * bu2f(g4[1]) + bu2f(b4[1]));
    o[2] = f2bu((bu2f(xi[2]) - m) * rstd * bu2f(g4[2]) + bu2f(b4[2]));
    o[3] = f2bu((bu2f(xi[3]) - m) * rstd * bu2f(g4[3]) + bu2f(b4[3]));
    *(us4*)((unsigned short*)out + v*4) = o;
  }
}

// LN2 apply (bf16 in/out) + accumulate LN3 stats (on the bf16-rounded values)
__global__ __launch_bounds__(256) void ln_b16_b16_stats(const bf16* __restrict__ in,
    const float* __restrict__ stats, const bf16* __restrict__ gamma,
    const bf16* __restrict__ beta, bf16* __restrict__ out, float* __restrict__ stats3)
{
  __shared__ float red[512];
  const int b = blockIdx.x >> 4;
  const float invN = 1.f / (float)(S_*D_);
  const float m    = stats[b*2] * invN;
  const float var  = stats[b*2+1] * invN - m*m;
  const float rstd = rsqrtf(var + 1e-5f);
  size_t v = (size_t)b * 65536 + (blockIdx.x & 15) * 4096 + threadIdx.x;
  float s_acc = 0.f, ss_acc = 0.f;
#pragma unroll 4
  for (int it = 0; it < 16; it++, v += 256) {
    us4 xi = *(const us4*)((const unsigned short*)in + v*4);
    size_t e = (v * 4) & (S_*D_ - 1);
    us4 g4 = *(const us4*)((const unsigned short*)gamma + e);
    us4 b4 = *(const us4*)((const unsigned short*)beta + e);
    float o0 = (bu2f(xi[0]) - m) * rstd * bu2f(g4[0]) + bu2f(b4[0]);
    float o1 = (bu2f(xi[1]) - m) * rstd * bu2f(g4[1]) + bu2f(b4[1]);
    float o2 = (bu2f(xi[2]) - m) * rstd * bu2f(g4[2]) + bu2f(b4[2]);
    float o3 = (bu2f(xi[3]) - m) * rstd * bu2f(g4[3]) + bu2f(b4[3]);
    us4 o;
    o[0] = f2bu(o0); o[1] = f2bu(o1); o[2] = f2bu(o2); o[3] = f2bu(o3);
    s_acc  += o0 + o1 + o2 + o3;
    ss_acc += o0*o0 + o1*o1 + o2*o2 + o3*o3;
    *(us4*)((unsigned short*)out + v*4) = o;
  }
  const int tid = threadIdx.x;
  red[tid] = s_acc; red[256 + tid] = ss_acc;
  __syncthreads();
  for (int st = 128; st; st >>= 1) {
    if (tid < st) { red[tid] += red[tid + st]; red[256 + tid] += red[256 + tid + st]; }
    __syncthreads();
  }
  if (tid == 0) {
    atomicAdd(&stats3[b*2],     red[0]);
    atomicAdd(&stats3[b*2 + 1], red[256]);
  }
}

// final LN: bf16 in, output dtype per flag
__global__ __launch_bounds__(256) void ln_apply_out(const bf16* __restrict__ in,
    const float* __restrict__ stats, const bf16* __restrict__ gamma,
    const bf16* __restrict__ beta, void* __restrict__ out, const int* __restrict__ flag)
{
  const bool f32 = (*flag != 0);
  const int b = blockIdx.x >> 4;
  const float invN = 1.f / (float)(S_*D_);
  const float m    = stats[b*2] * invN;
  const float var  = stats[b*2+1] * invN - m*m;
  const float rstd = rsqrtf(var + 1e-5f);
  size_t v = (size_t)b * 65536 + (blockIdx.x & 15) * 4096 + threadIdx.x;
#pragma unroll 4
  for (int it = 0; it < 16; it++, v += 256) {
    us4 xi = *(const us4*)((const unsigned short*)in + v*4);
    size_t e = (v * 4) & (S_*D_ - 1);
    us4 g4 = *(const us4*)((const unsigned short*)gamma + e);
    us4 b4 = *(const us4*)((const unsigned short*)beta + e);
    float4 o;
    o.x = (bu2f(xi[0]) - m) * rstd * bu2f(g4[0]) + bu2f(b4[0]);
    o.y = (bu2f(xi[1]) - m) * rstd * bu2f(g4[1]) + bu2f(b4[1]);
    o.z = (bu2f(xi[2]) - m) * rstd * bu2f(g4[2]) + bu2f(b4[2]);
    o.w = (bu2f(xi[3]) - m) * rstd * bu2f(g4[3]) + bu2f(b4[3]);
    if (f32) ((float4*)out)[v] = o;
    else {
      us4 ob;
      ob[0] = f2bu(o.x); ob[1] = f2bu(o.y); ob[2] = f2bu(o.z); ob[3] = f2bu(o.w);
      *(us4*)((unsigned short*)out + v*4) = ob;
    }
  }
}

// ---------------- launch ----------------
extern "C" void kernel_launch(void* const* d_in, const int* in_sizes, int n_in,
                              void* d_out, int out_size, void* d_ws, size_t ws_size,
                              hipStream_t stream)
{
  char* p = (char*)d_ws;
  auto alloc_b = [&](size_t elems) { void* r = p; p += elems * 2; return (bf16*)r; };
  auto alloc_f = [&](size_t elems) {
    p = (char*)(((uintptr_t)p + 15) & ~(uintptr_t)15); void* r = p; p += elems * 4; return (float*)r;
  };

  bf16* xb   = alloc_b(MSD);            // x bf16
  bf16* qkv  = alloc_b(3 * MSD);        // [M][1536] natural
  bf16* catb = alloc_b(MSD);
  bf16* wqkv = alloc_b(3 * 512 * 512);
  bf16* wo   = alloc_b(512 * 512);
  bf16* w1p  = alloc_b((size_t)FFP * 512);
  bf16* w2p  = alloc_b((size_t)FFP * FFP);
  bf16* w3p  = alloc_b((size_t)512 * FFP);
  bf16* gm   = alloc_b((size_t)S_ * D_);   // gamma bf16
  bf16* bt   = alloc_b((size_t)S_ * D_);   // beta  bf16
  float* bqkv= alloc_f(3 * 512);
  float* bo  = alloc_f(512);
  float* b1p = alloc_f(FFP);
  float* b2p = alloc_f(FFP);
  float* b3  = alloc_f(512);
  float* stats = alloc_f(192);          // stats1 | stats2 | stats3
  int*   flag  = (int*)alloc_f(16);
  if ((size_t)(p - (char*)d_ws) > ws_size) return;

  // intermediates aliased into dead regions:
  bf16* y1b = qkv;                      // LN1 out [M][512]   (qkv dead after attn)
  bf16* f1  = qkv + MSD;                // [M][FFP]
  bf16* f2  = qkv + MSD + (size_t)M_ * FFP;
  bf16* yA  = qkv + 2 * MSD;            // out-proj + residual (bf16)
  bf16* yB  = catb;                     // FFN3 + residual     (catb dead after out-proj)
  bf16* y2b = yA;                       // LN2 out             (yA dead after LN1)
  float* st1 = stats, *st2 = stats + 64, *st3 = stats + 128;

  detect_kernel<<<1, 256, 0, stream>>>((const unsigned short*)d_in[0], flag, stats);
  cvt_x8<<<2048, 256, 0, stream>>>(d_in[0], xb, flag);

  Segs sg;
  // {src, dst, srcRows, srcK, dstK, total}
  sg.s[0]  = { d_in[1],  wqkv,               512, 512, 512, 512*512 };
  sg.s[1]  = { d_in[3],  wqkv + 512*512,     512, 512, 512, 512*512 };
  sg.s[2]  = { d_in[5],  wqkv + 2*512*512,   512, 512, 512, 512*512 };
  sg.s[3]  = { d_in[7],  wo,                 512, 512, 512, 512*512 };
  sg.s[4]  = { d_in[9],  w1p,                FF_, 512, 512, FFP*512 };
  sg.s[5]  = { d_in[11], w2p,                FF_, FF_, FFP, FFP*FFP };
  sg.s[6]  = { d_in[13], w3p,                512, FF_, FFP, 512*FFP };
  sg.s[7]  = { d_in[2],  bqkv,               1, 512, 512, 512 };
  sg.s[8]  = { d_in[4],  bqkv + 512,         1, 512, 512, 512 };
  sg.s[9]  = { d_in[6],  bqkv + 1024,        1, 512, 512, 512 };
  sg.s[10] = { d_in[8],  bo,                 1, 512, 512, 512 };
  sg.s[11] = { d_in[10], b1p,                1, FF_, FFP, FFP };
  sg.s[12] = { d_in[12], b2p,                1, FF_, FFP, FFP };
  sg.s[13] = { d_in[14], b3,                 1, 512, 512, 512 };
  sg.s[14] = { d_in[15], gm,                 1, S_*D_, S_*D_, S_*D_ };
  sg.s[15] = { d_in[16], bt,                 1, S_*D_, S_*D_, S_*D_ };
  sg.isbf = 0xC07F;                     // weights + gamma/beta are bf16
  cvt_all<<<1024, 256, 0, stream>>>(sg, flag);

  dim3 blk(256);

  // fused QKV projection: plain GEMM, natural output [M][1536]
  // weight rows for q:0-511(wq), k:512-1023(wk), v:1024-1535(wv) match column ids
  gemm_mfma<0, 0><<<dim3(M_/128, NQKV/128), blk, 0, stream>>>(
      xb, wqkv, bqkv, nullptr, qkv, M_, NQKV, 512, nullptr);

  attn_lds<<<B_*H_, 1024, 0, stream>>>(qkv, catb);

  // output projection + residual x -> bf16 yA, fused LN1 stats
  gemm_mfma<2, 1><<<dim3(M_/128, 4), blk, 0, stream>>>(
      catb, wo, bo, xb, yA, M_, 512, 512, st1);

  ln_b16_b16<<<512, blk, 0, stream>>>(yA, st1, gm, bt, y1b);

  // FFN (padded to 256)
  gemm_mfma<1, 0><<<dim3(M_/128, 2), blk, 0, stream>>>(
      y1b, w1p, b1p, nullptr, f1, M_, FFP, 512, nullptr);
  gemm_mfma<1, 0><<<dim3(M_/128, 2), blk, 0, stream>>>(
      f1, w2p, b2p, nullptr, f2, M_, FFP, FFP, nullptr);
  gemm_mfma<2, 1><<<dim3(M_/128, 4), blk, 0, stream>>>(
      f2, w3p, b3, y1b, yB, M_, 512, FFP, st2);

  // LN2 (apply + LN3 stats) -> bf16 y2, LN3 -> out
  ln_b16_b16_stats<<<512, blk, 0, stream>>>(yB, st2, gm, bt, y2b, st3);
  ln_apply_out<<<512, blk, 0, stream>>>(y2b, st3, gm, bt, d_out, flag);
}

// Round 11
// 279.205 us; speedup vs baseline: 1.4719x; 1.4719x over previous
//
#include <hip/hip_runtime.h>
#include <hip/hip_bf16.h>
#include <stdint.h>

// encoder_layer: B=32,S=512,D=512,H=8,DK=64,FF=200. bf16 MFMA, fp32 LN stats.
#define B_  32
#define S_  512
#define D_  512
#define H_  8
#define DK_ 64
#define FF_ 200
#define FFP 256                 // FF padded to 256 (zero-fill) -> unguarded GEMMs
#define M_  (B_*S_)             // 16384
#define MSD ((size_t)B_*S_*D_)  // 8388608
#define NQKV 1536

typedef __hip_bfloat16 bf16;
typedef __attribute__((ext_vector_type(8))) short short8;
typedef __attribute__((ext_vector_type(4))) float f32x4;
typedef __attribute__((ext_vector_type(4))) unsigned short us4;

__device__ inline float b2f(bf16 v) { return __bfloat162float(v); }
__device__ inline bf16  f2b(float v){ return __float2bfloat16(v); }
__device__ inline unsigned short f2bu(float v) {
  union { bf16 h; unsigned short u; } cv; cv.h = __float2bfloat16(v); return cv.u;
}
__device__ inline float bu2f(unsigned short u) {
  union { unsigned short u; bf16 h; } cv; cv.u = u; return b2f(cv.h);
}
__device__ __forceinline__ void async16(const bf16* g, bf16* l) {
  __builtin_amdgcn_global_load_lds((const __attribute__((address_space(1))) void*)g,
                                   (__attribute__((address_space(3))) void*)l, 16, 0, 0);
}

// ---------------- dtype detection (flag=1 -> fp32 inputs) + stats zero ----------------
__global__ void detect_kernel(const unsigned short* __restrict__ xu, int* __restrict__ flag,
                              float* __restrict__ stats) {
  __shared__ int mx[256];
  const int tid = threadIdx.x;
  if (tid < 192) stats[tid] = 0.f;
  int m = 0;
  for (int i = tid * 2; i < 8192; i += 512) {
    int e = (xu[i] >> 7) & 0xFF;
    m = m > e ? m : e;
  }
  mx[tid] = m;
  __syncthreads();
  for (int st = 128; st; st >>= 1) {
    if (tid < st) mx[tid] = mx[tid] > mx[tid + st] ? mx[tid] : mx[tid + st];
    __syncthreads();
  }
  if (tid == 0) *flag = (mx[0] >= 0xC0) ? 1 : 0;
}

// ---------------- x convert, 8 elems/thread ----------------
__global__ __launch_bounds__(256) void cvt_x8(const void* __restrict__ in, bf16* __restrict__ out,
                                              const int* __restrict__ flag) {
  const bool f32in = (*flag != 0);
  size_t i = ((size_t)blockIdx.x * 256 + threadIdx.x) * 8;
  const size_t stride = (size_t)gridDim.x * 256 * 8;
  for (; i < MSD; i += stride) {
    if (f32in) {
      const float4 a = ((const float4*)in)[i/4];
      const float4 b = ((const float4*)in)[i/4 + 1];
      uint4 o; unsigned short* po = (unsigned short*)&o;
      po[0]=f2bu(a.x); po[1]=f2bu(a.y); po[2]=f2bu(a.z); po[3]=f2bu(a.w);
      po[4]=f2bu(b.x); po[5]=f2bu(b.y); po[6]=f2bu(b.z); po[7]=f2bu(b.w);
      *(uint4*)((unsigned short*)out + i) = o;
    } else {
      *(uint4*)((unsigned short*)out + i) = *(const uint4*)((const unsigned short*)in + i);
    }
  }
}

// ---------------- merged weight/bias/gamma convert with zero-padding ----------------
struct Seg { const void* src; void* dst; int srcRows, srcK, dstK, total; };
struct Segs { Seg s[16]; unsigned int isbf; };

__global__ __launch_bounds__(256) void cvt_all(Segs sg, const int* __restrict__ flag) {
  const bool f32in = (*flag != 0);
  const int seg = blockIdx.x & 15;
  const Seg sd = sg.s[seg];
  const int stride = (gridDim.x >> 4) * 256;
  const bool nopad = (sd.srcK == sd.dstK);
  for (int i = (blockIdx.x >> 4) * 256 + threadIdx.x; i < sd.total; i += stride) {
    int sidx; bool valid;
    if (nopad) { sidx = i; valid = (i < sd.srcRows * sd.srcK); }
    else {
      int r = i / sd.dstK, c = i - r * sd.dstK;
      valid = (r < sd.srcRows) && (c < sd.srcK);
      sidx = r * sd.srcK + c;
    }
    float v = 0.f;
    if (valid) v = f32in ? ((const float*)sd.src)[sidx] : b2f(((const bf16*)sd.src)[sidx]);
    if (sg.isbf & (1u << seg)) ((unsigned short*)sd.dst)[i] = f2bu(v);
    else                       ((float*)sd.dst)[i] = v;
  }
}

// ---------------- bf16 MFMA GEMM: 3-plane pipeline, SINGLE barrier per K-step --------
// C[m,n] = sum_k A[m,k]*W[n,k] + bias[n].  Requires M%128==0, N%128==0, K%32==0, K>=96.
// MODE: 0=plain, 1=relu, 2=+residual R(bf16)
// STATS: accumulate per-batch sum/sumsq of stored value into stats[b*2(+1)]
// Grid is (M/128, N/128) M-fast: blocks sharing an A-panel land on the SAME XCD.
// R8's proven form (273.6us best). R9 4-plane regressed (occupancy 24.5->16.6%,
// FETCH 29->36MB): K-loop is LDS-BW-bound (~96KB LDS traffic per CU-iter ~= the
// 1075cyc period) -> deeper prefetch cannot help at this tile size.
template<int MODE, int STATS>
__global__ __launch_bounds__(256) void gemm_mfma(
    const bf16* __restrict__ A, const bf16* __restrict__ W, const float* __restrict__ bias,
    const bf16* __restrict__ R, bf16* __restrict__ C, int M, int N, int K,
    float* __restrict__ stats)
{
  __shared__ __align__(16) char smem[49152];
  bf16*  As  = (bf16*)smem;                 // [3][128][32]  24 KB
  bf16*  Bs  = (bf16*)(smem + 24576);       // [3][128][32]  24 KB
  float* Lf  = (float*)smem;                // [32][132] fp32 epilogue staging (16896 B)
  float* red = (float*)(smem + 16896);      // 512 floats stats reduction

  const int tid  = threadIdx.x;
  const int bm   = blockIdx.x * 128;
  const int bn   = blockIdx.y * 128;
  const int w    = tid >> 6;
  const int lane = tid & 63;
  const int qd   = lane >> 4;
  const int ln   = lane & 15;
  const int wr   = (w >> 1) * 64;
  const int wc   = (w & 1) * 64;

  const int r0 = lane >> 2;
  const int ch = (lane & 3) * 8;
  const bf16* Ag0 = A + (size_t)(bm + w*16 + r0) * K + ch;
  const bf16* Ag1 = Ag0 + (size_t)64 * K;
  const bf16* Bg0 = W + (size_t)(bn + w*16 + r0) * K + ch;
  const bf16* Bg1 = Bg0 + (size_t)64 * K;
  const int lo = w*512 + lane*8;            // offset within a 4096-elem plane

  f32x4 acc[4][4] = {};
  const int nt = K >> 5;

  // prologue: stage tiles 0,1 into planes 0,1
  async16(Ag0, As + lo);
  async16(Ag1, As + lo + 2048);
  async16(Bg0, Bs + lo);
  async16(Bg1, Bs + lo + 2048);
  async16(Ag0 + 32, As + 4096 + lo);
  async16(Ag1 + 32, As + 4096 + lo + 2048);
  async16(Bg0 + 32, Bs + 4096 + lo);
  async16(Bg1 + 32, Bs + 4096 + lo + 2048);

  int pcur = 0;                              // plane holding tile t
  for (int t = 0; t < nt; t++) {
    if (t + 1 < nt) {
      asm volatile("s_waitcnt vmcnt(4)" ::: "memory");   // tile-t landed; t+1 in flight
    } else {
      asm volatile("s_waitcnt vmcnt(0)" ::: "memory");
    }
    __builtin_amdgcn_s_barrier();                        // tile t visible to all waves

    const int cur = pcur << 12;
    short8 af[4], bfr[4];
#pragma unroll
    for (int i = 0; i < 4; i++) af[i]  = *(const short8*)(As + cur + (wr + i*16 + ln)*32 + qd*8);
#pragma unroll
    for (int j = 0; j < 4; j++) bfr[j] = *(const short8*)(Bs + cur + (wc + j*16 + ln)*32 + qd*8);

    if (t + 2 < nt) {
      int pst = pcur - 1; if (pst < 0) pst = 2;   // (pcur+2)%3
      const int nxt = pst << 12;
      const int k0  = (t + 2) << 5;
      async16(Ag0 + k0, As + nxt + lo);
      async16(Ag1 + k0, As + nxt + lo + 2048);
      async16(Bg0 + k0, Bs + nxt + lo);
      async16(Bg1 + k0, Bs + nxt + lo + 2048);
    }

#pragma unroll
    for (int i = 0; i < 4; i++)
#pragma unroll
      for (int j = 0; j < 4; j++)
        acc[i][j] = __builtin_amdgcn_mfma_f32_16x16x32_bf16(af[i], bfr[j], acc[i][j], 0, 0, 0);

    pcur = pcur + 1 == 3 ? 0 : pcur + 1;
  }
  __syncthreads();                           // all reads done before Lf aliases planes

  // ---- epilogue: 4 chunks of 32 rows; stage fp32 in LDS, readback coalesced ----
  float s_acc = 0.f, ss_acc = 0.f;
  const int lrbase = (w >> 1)*16 + qd*4;
#pragma unroll
  for (int i = 0; i < 4; i++) {
#pragma unroll
    for (int j = 0; j < 4; j++) {
      const int col = wc + j*16 + ln;
#pragma unroll
      for (int rg = 0; rg < 4; rg++)
        Lf[(lrbase + rg)*132 + col] = acc[i][j][rg];
    }
    __syncthreads();
    // readback: 2 pairs of float4 per thread -> one 16B bf16 store each
#pragma unroll
    for (int pz = 0; pz < 2; pz++) {
      const int q   = tid + pz*256;
      const int r   = q >> 4;            // 0..31
      const int nof = (q & 15)*8;        // 0..120
      const int m   = bm + (r >> 4)*64 + i*16 + (r & 15);
      const int n   = bn + nof;
      f32x4 v0 = *(const f32x4*)(Lf + r*132 + nof);
      f32x4 v1 = *(const f32x4*)(Lf + r*132 + nof + 4);
      f32x4 b0 = *(const f32x4*)(bias + n);
      f32x4 b1 = *(const f32x4*)(bias + n + 4);
      float vals[8];
#pragma unroll
      for (int e = 0; e < 4; e++) { vals[e] = v0[e] + b0[e]; vals[4+e] = v1[e] + b1[e]; }
      if (MODE == 1) {
#pragma unroll
        for (int e = 0; e < 8; e++) vals[e] = fmaxf(vals[e], 0.f);
      }
      if (MODE == 2) {
        const uint4 rv = *(const uint4*)((const unsigned short*)R + (size_t)m * N + n);
        const unsigned short* rp = (const unsigned short*)&rv;
#pragma unroll
        for (int e = 0; e < 8; e++) vals[e] += bu2f(rp[e]);
      }
      if (STATS) {
#pragma unroll
        for (int e = 0; e < 8; e++) { s_acc += vals[e]; ss_acc += vals[e]*vals[e]; }
      }
      uint4 o; unsigned short* op = (unsigned short*)&o;
#pragma unroll
      for (int e = 0; e < 8; e++) op[e] = f2bu(vals[e]);
      *(uint4*)((unsigned short*)C + (size_t)m * N + n) = o;
    }
    __syncthreads();
  }

  if (STATS) {
    red[tid] = s_acc; red[256 + tid] = ss_acc;
    __syncthreads();
    for (int st = 128; st; st >>= 1) {
      if (tid < st) { red[tid] += red[tid + st]; red[256 + tid] += red[256 + tid + st]; }
      __syncthreads();
    }
    if (tid == 0) {
      const int b = bm >> 9;
      atomicAdd(&stats[b*2],     red[0]);
      atomicAdd(&stats[b*2 + 1], red[256]);
    }
  }
}

// ---------------- attention: chunked K/V staging overlapped with compute (T14) -------
// qkv: [M][1536] = [b*512+s][q(512)|k(512)|v(512)], head h at columns h*64.
// One block per (b,h); 16 waves; each wave does 32 queries x 512 keys.
// Keys split in 2 chunks of 256. Prologue stages chunk 0 only; after the first sync,
// chunk-1 K is issued via async16 and chunk-1 V into registers, then chunk-0 compute
// runs (st 0..7) hiding the staging latency; vmcnt(0) -> V-transpose writes ->
// lgkmcnt(0) + raw s_barrier (counted waits keep the prefetch alive; __syncthreads
// would drain it) -> chunk-1 compute. Disjoint LDS regions -> no races.
// NOTE R10's 4-chunk variant (fully-unrolled c-loop, 3 held uint4) spilled to
// scratch (VGPR 64 + 200MB spill traffic, attn 146us) -- do NOT extend this
// pattern by unrolling more chunks; 2 chunks is the codegen-safe depth.
__global__ __launch_bounds__(1024, 4) void attn_lds(const bf16* __restrict__ qkv,
                                                    bf16* __restrict__ cat)
{
  __shared__ bf16 Ks[2 * 512 * 32];     // 64 KB [ks][key][32]
  __shared__ bf16 Vs[64 * 520];         // 65 KB [dk][key] padded
  __shared__ bf16 pbuf[16][16][40];     // 20 KB per-wave prob staging

  const int tid  = threadIdx.x;
  const int w    = tid >> 6;
  const int lane = tid & 63;
  const int qd   = lane >> 4;
  const int ln   = lane & 15;
  const int bh   = blockIdx.x;
  const int b    = bh >> 3, h = bh & 7;
  const bf16* base = qkv + (size_t)b * 512 * NQKV + h * 64;

  // --- stage K chunk 0 (keys 0..255): [ks][key][32] layout ---
#pragma unroll
  for (int r = 0; r < 2; r++) {
    int c = tid + r*1024;                       // [0,2048)
    int part = c & 3, key = (c >> 2) & 255, ks = c >> 10;
    async16(base + (size_t)key * NQKV + 512 + ks*32 + part*8,
            Ks + ks*16384 + key*32 + part*8);
  }
  // --- stage V chunk 0 transposed: Vs[dk][key], conflict-free lane<->key mapping ---
#pragma unroll
  for (int r = 0; r < 2; r++) {
    int c = tid + r*1024;
    int dkg = c >> 8, key = c & 255;
    uint4 vv = *(const uint4*)(base + (size_t)key * NQKV + 1024 + dkg*8);
    const unsigned short* pv = (const unsigned short*)&vv;
#pragma unroll
    for (int j = 0; j < 8; j++)
      *(unsigned short*)&Vs[(dkg*8 + j)*520 + key] = pv[j];
  }
  // --- Q B-frags for this wave's 32 queries ---
  short8 bq[2][2];
#pragma unroll
  for (int qt = 0; qt < 2; qt++)
#pragma unroll
    for (int ks = 0; ks < 2; ks++)
      bq[qt][ks] = *(const short8*)(base + (size_t)(w*32 + qt*16 + ln) * NQKV + ks*32 + qd*8);

  __syncthreads();                              // chunk 0 visible

  // --- issue chunk 1 staging (keys 256..511): K direct-to-LDS, V into registers ---
#pragma unroll
  for (int r = 0; r < 2; r++) {
    int c = tid + r*1024;
    int part = c & 3, key = 256 + ((c >> 2) & 255), ks = c >> 10;
    async16(base + (size_t)key * NQKV + 512 + ks*32 + part*8,
            Ks + ks*16384 + key*32 + part*8);
  }
  uint4 vhold[2]; int vdst[2];
#pragma unroll
  for (int r = 0; r < 2; r++) {
    int c = tid + r*1024;
    int dkg = c >> 8, key = 256 + (c & 255);
    vhold[r] = *(const uint4*)(base + (size_t)key * NQKV + 1024 + dkg*8);
    vdst[r] = dkg*8*520 + key;
  }
  asm volatile("" ::: "memory");                // pin load issue before compute

  bf16 (*pb)[40] = pbuf[w];
  f32x4 o[2][4] = {};
  float l[2] = {0.f, 0.f};

  for (int half = 0; half < 2; half++) {
    for (int st = half*8; st < half*8 + 8; st++) {
      short8 ak[2][2];
#pragma unroll
      for (int kt = 0; kt < 2; kt++)
#pragma unroll
        for (int ks = 0; ks < 2; ks++)
          ak[kt][ks] = *(const short8*)(Ks + ks*16384 + (st*32 + kt*16 + ln)*32 + qd*8);
      f32x4 s[2][2] = {};
#pragma unroll
      for (int kt = 0; kt < 2; kt++)
#pragma unroll
        for (int qt = 0; qt < 2; qt++) {
          s[kt][qt] = __builtin_amdgcn_mfma_f32_16x16x32_bf16(ak[kt][0], bq[qt][0], s[kt][qt], 0, 0, 0);
          s[kt][qt] = __builtin_amdgcn_mfma_f32_16x16x32_bf16(ak[kt][1], bq[qt][1], s[kt][qt], 0, 0, 0);
        }
      float e[2][2][4];
#pragma unroll
      for (int kt = 0; kt < 2; kt++)
#pragma unroll
        for (int qt = 0; qt < 2; qt++)
#pragma unroll
          for (int rg = 0; rg < 4; rg++) {
            float ev = __expf(s[kt][qt][rg] * 0.125f);
            e[kt][qt][rg] = ev;
            l[qt] += ev;
          }
#pragma unroll
      for (int qt = 0; qt < 2; qt++) {
#pragma unroll
        for (int kt = 0; kt < 2; kt++) {
          uint2 pk;
          pk.x = (unsigned)f2bu(e[kt][qt][0]) | ((unsigned)f2bu(e[kt][qt][1]) << 16);
          pk.y = (unsigned)f2bu(e[kt][qt][2]) | ((unsigned)f2bu(e[kt][qt][3]) << 16);
          *(uint2*)&pb[ln][kt*16 + qd*4] = pk;
        }
        short8 ap = *(const short8*)&pb[ln][qd*8];
#pragma unroll
        for (int nt = 0; nt < 4; nt++) {
          short8 bv = *(const short8*)(Vs + (nt*16 + ln)*520 + st*32 + qd*8);
          o[qt][nt] = __builtin_amdgcn_mfma_f32_16x16x32_bf16(ap, bv, o[qt][nt], 0, 0, 0);
        }
      }
    }
    if (half == 0) {
      // land chunk 1: V regs -> LDS (K async16 already targeted LDS directly)
      asm volatile("s_waitcnt vmcnt(0)" ::: "memory");
#pragma unroll
      for (int r = 0; r < 2; r++) {
        const unsigned short* pv = (const unsigned short*)&vhold[r];
#pragma unroll
        for (int j = 0; j < 8; j++)
          *(unsigned short*)&Vs[vdst[r] + j*520] = pv[j];
      }
      asm volatile("s_waitcnt lgkmcnt(0)" ::: "memory");
      __builtin_amdgcn_s_barrier();             // chunk 1 visible to all waves
    }
  }

#pragma unroll
  for (int qt = 0; qt < 2; qt++) {
    l[qt] += __shfl_xor(l[qt], 16);
    l[qt] += __shfl_xor(l[qt], 32);
  }
  float inv0 = 1.f / l[0], inv1 = 1.f / l[1];

  const size_t crow0 = (size_t)(b*S_ + w*32) * D_ + h*DK_;
#pragma unroll
  for (int qt = 0; qt < 2; qt++) {
#pragma unroll
    for (int rg = 0; rg < 4; rg++) {
      float ivv = __shfl(qt ? inv1 : inv0, qd*4 + rg);
      int r = qt*16 + qd*4 + rg;
      bf16* cp = cat + crow0 + (size_t)r * D_ + ln;
#pragma unroll
      for (int nt = 0; nt < 4; nt++) cp[nt*16] = f2b(o[qt][nt][rg] * ivv);
    }
  }
}

// ---------------- LN applies (bf16 in), stats precomputed, bf16 gamma/beta ----------------
__global__ __launch_bounds__(256) void ln_b16_b16(const bf16* __restrict__ in,
    const float* __restrict__ stats, const bf16* __restrict__ gamma,
    const bf16* __restrict__ beta, bf16* __restrict__ out)
{
  const int b = blockIdx.x >> 4;
  const float invN = 1.f / (float)(S_*D_);
  const float m    = stats[b*2] * invN;
  const float var  = stats[b*2+1] * invN - m*m;
  const float rstd = rsqrtf(var + 1e-5f);
  size_t v = (size_t)b * 65536 + (blockIdx.x & 15) * 4096 + threadIdx.x;
#pragma unroll 4
  for (int it = 0; it < 16; it++, v += 256) {
    us4 xi = *(const us4*)((const unsigned short*)in + v*4);
    size_t e = (v * 4) & (S_*D_ - 1);
    us4 g4 = *(const us4*)((const unsigned short*)gamma + e);
    us4 b4 = *(const us4*)((const unsigned short*)beta + e);
    us4 o;
    o[0] = f2bu((bu2f(xi[0]) - m) * rstd * bu2f(g4[0]) + bu2f(b4[0]));
    o[1] = f2bu((bu2f(xi[1]) - m) * rstd * bu2f(g4[1]) + bu2f(b4[1]));
    o[2] = f2bu((bu2f(xi[2]) - m) * rstd * bu2f(g4[2]) + bu2f(b4[2]));
    o[3] = f2bu((bu2f(xi[3]) - m) * rstd * bu2f(g4[3]) + bu2f(b4[3]));
    *(us4*)((unsigned short*)out + v*4) = o;
  }
}

// LN2 apply (bf16 in/out) + accumulate LN3 stats (on the bf16-rounded values)
__global__ __launch_bounds__(256) void ln_b16_b16_stats(const bf16* __restrict__ in,
    const float* __restrict__ stats, const bf16* __restrict__ gamma,
    const bf16* __restrict__ beta, bf16* __restrict__ out, float* __restrict__ stats3)
{
  __shared__ float red[512];
  const int b = blockIdx.x >> 4;
  const float invN = 1.f / (float)(S_*D_);
  const float m    = stats[b*2] * invN;
  const float var  = stats[b*2+1] * invN - m*m;
  const float rstd = rsqrtf(var + 1e-5f);
  size_t v = (size_t)b * 65536 + (blockIdx.x & 15) * 4096 + threadIdx.x;
  float s_acc = 0.f, ss_acc = 0.f;
#pragma unroll 4
  for (int it = 0; it < 16; it++, v += 256) {
    us4 xi = *(const us4*)((const unsigned short*)in + v*4);
    size_t e = (v * 4) & (S_*D_ - 1);
    us4 g4 = *(const us4*)((const unsigned short*)gamma + e);
    us4 b4 = *(const us4*)((const unsigned short*)beta + e);
    float o0 = (bu2f(xi[0]) - m) * rstd * bu2f(g4[0]) + bu2f(b4[0]);
    float o1 = (bu2f(xi[1]) - m) * rstd * bu2f(g4[1]) + bu2f(b4[1]);
    float o2 = (bu2f(xi[2]) - m) * rstd * bu2f(g4[2]) + bu2f(b4[2]);
    float o3 = (bu2f(xi[3]) - m) * rstd * bu2f(g4[3]) + bu2f(b4[3]);
    us4 o;
    o[0] = f2bu(o0); o[1] = f2bu(o1); o[2] = f2bu(o2); o[3] = f2bu(o3);
    s_acc  += o0 + o1 + o2 + o3;
    ss_acc += o0*o0 + o1*o1 + o2*o2 + o3*o3;
    *(us4*)((unsigned short*)out + v*4) = o;
  }
  const int tid = threadIdx.x;
  red[tid] = s_acc; red[256 + tid] = ss_acc;
  __syncthreads();
  for (int st = 128; st; st >>= 1) {
    if (tid < st) { red[tid] += red[tid + st]; red[256 + tid] += red[256 + tid + st]; }
    __syncthreads();
  }
  if (tid == 0) {
    atomicAdd(&stats3[b*2],     red[0]);
    atomicAdd(&stats3[b*2 + 1], red[256]);
  }
}

// final LN: bf16 in, output dtype per flag
__global__ __launch_bounds__(256) void ln_apply_out(const bf16* __restrict__ in,
    const float* __restrict__ stats, const bf16* __restrict__ gamma,
    const bf16* __restrict__ beta, void* __restrict__ out, const int* __restrict__ flag)
{
  const bool f32 = (*flag != 0);
  const int b = blockIdx.x >> 4;
  const float invN = 1.f / (float)(S_*D_);
  const float m    = stats[b*2] * invN;
  const float var  = stats[b*2+1] * invN - m*m;
  const float rstd = rsqrtf(var + 1e-5f);
  size_t v = (size_t)b * 65536 + (blockIdx.x & 15) * 4096 + threadIdx.x;
#pragma unroll 4
  for (int it = 0; it < 16; it++, v += 256) {
    us4 xi = *(const us4*)((const unsigned short*)in + v*4);
    size_t e = (v * 4) & (S_*D_ - 1);
    us4 g4 = *(const us4*)((const unsigned short*)gamma + e);
    us4 b4 = *(const us4*)((const unsigned short*)beta + e);
    float4 o;
    o.x = (bu2f(xi[0]) - m) * rstd * bu2f(g4[0]) + bu2f(b4[0]);
    o.y = (bu2f(xi[1]) - m) * rstd * bu2f(g4[1]) + bu2f(b4[1]);
    o.z = (bu2f(xi[2]) - m) * rstd * bu2f(g4[2]) + bu2f(b4[2]);
    o.w = (bu2f(xi[3]) - m) * rstd * bu2f(g4[3]) + bu2f(b4[3]);
    if (f32) ((float4*)out)[v] = o;
    else {
      us4 ob;
      ob[0] = f2bu(o.x); ob[1] = f2bu(o.y); ob[2] = f2bu(o.z); ob[3] = f2bu(o.w);
      *(us4*)((unsigned short*)out + v*4) = ob;
    }
  }
}

// ---------------- launch ----------------
extern "C" void kernel_launch(void* const* d_in, const int* in_sizes, int n_in,
                              void* d_out, int out_size, void* d_ws, size_t ws_size,
                              hipStream_t stream)
{
  char* p = (char*)d_ws;
  auto alloc_b = [&](size_t elems) { void* r = p; p += elems * 2; return (bf16*)r; };
  auto alloc_f = [&](size_t elems) {
    p = (char*)(((uintptr_t)p + 15) & ~(uintptr_t)15); void* r = p; p += elems * 4; return (float*)r;
  };

  bf16* xb   = alloc_b(MSD);            // x bf16
  bf16* qkv  = alloc_b(3 * MSD);        // [M][1536] natural
  bf16* catb = alloc_b(MSD);
  bf16* wqkv = alloc_b(3 * 512 * 512);
  bf16* wo   = alloc_b(512 * 512);
  bf16* w1p  = alloc_b((size_t)FFP * 512);
  bf16* w2p  = alloc_b((size_t)FFP * FFP);
  bf16* w3p  = alloc_b((size_t)512 * FFP);
  bf16* gm   = alloc_b((size_t)S_ * D_);   // gamma bf16
  bf16* bt   = alloc_b((size_t)S_ * D_);   // beta  bf16
  float* bqkv= alloc_f(3 * 512);
  float* bo  = alloc_f(512);
  float* b1p = alloc_f(FFP);
  float* b2p = alloc_f(FFP);
  float* b3  = alloc_f(512);
  float* stats = alloc_f(192);          // stats1 | stats2 | stats3
  int*   flag  = (int*)alloc_f(16);
  if ((size_t)(p - (char*)d_ws) > ws_size) return;

  // intermediates aliased into dead regions:
  bf16* y1b = qkv;                      // LN1 out [M][512]   (qkv dead after attn)
  bf16* f1  = qkv + MSD;                // [M][FFP]
  bf16* f2  = qkv + MSD + (size_t)M_ * FFP;
  bf16* yA  = qkv + 2 * MSD;            // out-proj + residual (bf16)
  bf16* yB  = catb;                     // FFN3 + residual     (catb dead after out-proj)
  bf16* y2b = yA;                       // LN2 out             (yA dead after LN1)
  float* st1 = stats, *st2 = stats + 64, *st3 = stats + 128;

  detect_kernel<<<1, 256, 0, stream>>>((const unsigned short*)d_in[0], flag, stats);
  cvt_x8<<<2048, 256, 0, stream>>>(d_in[0], xb, flag);

  Segs sg;
  // {src, dst, srcRows, srcK, dstK, total}
  sg.s[0]  = { d_in[1],  wqkv,               512, 512, 512, 512*512 };
  sg.s[1]  = { d_in[3],  wqkv + 512*512,     512, 512, 512, 512*512 };
  sg.s[2]  = { d_in[5],  wqkv + 2*512*512,   512, 512, 512, 512*512 };
  sg.s[3]  = { d_in[7],  wo,                 512, 512, 512, 512*512 };
  sg.s[4]  = { d_in[9],  w1p,                FF_, 512, 512, FFP*512 };
  sg.s[5]  = { d_in[11], w2p,                FF_, FF_, FFP, FFP*FFP };
  sg.s[6]  = { d_in[13], w3p,                512, FF_, FFP, 512*FFP };
  sg.s[7]  = { d_in[2],  bqkv,               1, 512, 512, 512 };
  sg.s[8]  = { d_in[4],  bqkv + 512,         1, 512, 512, 512 };
  sg.s[9]  = { d_in[6],  bqkv + 1024,        1, 512, 512, 512 };
  sg.s[10] = { d_in[8],  bo,                 1, 512, 512, 512 };
  sg.s[11] = { d_in[10], b1p,                1, FF_, FFP, FFP };
  sg.s[12] = { d_in[12], b2p,                1, FF_, FFP, FFP };
  sg.s[13] = { d_in[14], b3,                 1, 512, 512, 512 };
  sg.s[14] = { d_in[15], gm,                 1, S_*D_, S_*D_, S_*D_ };
  sg.s[15] = { d_in[16], bt,                 1, S_*D_, S_*D_, S_*D_ };
  sg.isbf = 0xC07F;                     // weights + gamma/beta are bf16
  cvt_all<<<1024, 256, 0, stream>>>(sg, flag);

  dim3 blk(256);

  // fused QKV projection: plain GEMM, natural output [M][1536]
  // weight rows for q:0-511(wq), k:512-1023(wk), v:1024-1535(wv) match column ids
  gemm_mfma<0, 0><<<dim3(M_/128, NQKV/128), blk, 0, stream>>>(
      xb, wqkv, bqkv, nullptr, qkv, M_, NQKV, 512, nullptr);

  attn_lds<<<B_*H_, 1024, 0, stream>>>(qkv, catb);

  // output projection + residual x -> bf16 yA, fused LN1 stats
  gemm_mfma<2, 1><<<dim3(M_/128, 4), blk, 0, stream>>>(
      catb, wo, bo, xb, yA, M_, 512, 512, st1);

  ln_b16_b16<<<512, blk, 0, stream>>>(yA, st1, gm, bt, y1b);

  // FFN (padded to 256)
  gemm_mfma<1, 0><<<dim3(M_/128, 2), blk, 0, stream>>>(
      y1b, w1p, b1p, nullptr, f1, M_, FFP, 512, nullptr);
  gemm_mfma<1, 0><<<dim3(M_/128, 2), blk, 0, stream>>>(
      f1, w2p, b2p, nullptr, f2, M_, FFP, FFP, nullptr);
  gemm_mfma<2, 1><<<dim3(M_/128, 4), blk, 0, stream>>>(
      f2, w3p, b3, y1b, yB, M_, 512, FFP, st2);

  // LN2 (apply + LN3 stats) -> bf16 y2, LN3 -> out
  ln_b16_b16_stats<<<512, blk, 0, stream>>>(yB, st2, gm, bt, y2b, st3);
  ln_apply_out<<<512, blk, 0, stream>>>(y2b, st3, gm, bt, d_out, flag);
}

// Round 12
// 273.167 us; speedup vs baseline: 1.5045x; 1.0221x over previous
//
#include <hip/hip_runtime.h>
#include <hip/hip_bf16.h>
#include <stdint.h>

// encoder_layer: B=32,S=512,D=512,H=8,DK=64,FF=200. bf16 MFMA, fp32 LN stats.
#define B_  32
#define S_  512
#define D_  512
#define H_  8
#define DK_ 64
#define FF_ 200
#define FFP 256                 // FF padded to 256 (zero-fill) -> unguarded GEMMs
#define M_  (B_*S_)             // 16384
#define MSD ((size_t)B_*S_*D_)  // 8388608
#define NQKV 1536

typedef __hip_bfloat16 bf16;
typedef __attribute__((ext_vector_type(8))) short short8;
typedef __attribute__((ext_vector_type(4))) float f32x4;
typedef __attribute__((ext_vector_type(4))) unsigned short us4;

__device__ inline float b2f(bf16 v) { return __bfloat162float(v); }
__device__ inline bf16  f2b(float v){ return __float2bfloat16(v); }
__device__ inline unsigned short f2bu(float v) {
  union { bf16 h; unsigned short u; } cv; cv.h = __float2bfloat16(v); return cv.u;
}
__device__ inline float bu2f(unsigned short u) {
  union { unsigned short u; bf16 h; } cv; cv.u = u; return b2f(cv.h);
}
__device__ __forceinline__ void async16(const bf16* g, bf16* l) {
  __builtin_amdgcn_global_load_lds((const __attribute__((address_space(1))) void*)g,
                                   (__attribute__((address_space(3))) void*)l, 16, 0, 0);
}

// ---------------- dtype detection (flag=1 -> fp32 inputs) + stats zero ----------------
__global__ void detect_kernel(const unsigned short* __restrict__ xu, int* __restrict__ flag,
                              float* __restrict__ stats) {
  __shared__ int mx[256];
  const int tid = threadIdx.x;
  if (tid < 160) { stats[tid] = 0.f; stats[tid + 160] = 0.f; }   // zero 320 floats
  int m = 0;
  for (int i = tid * 2; i < 8192; i += 512) {
    int e = (xu[i] >> 7) & 0xFF;
    m = m > e ? m : e;
  }
  mx[tid] = m;
  __syncthreads();
  for (int st = 128; st; st >>= 1) {
    if (tid < st) mx[tid] = mx[tid] > mx[tid + st] ? mx[tid] : mx[tid + st];
    __syncthreads();
  }
  if (tid == 0) *flag = (mx[0] >= 0xC0) ? 1 : 0;
}

// ---------------- x convert, 8 elems/thread ----------------
__global__ __launch_bounds__(256) void cvt_x8(const void* __restrict__ in, bf16* __restrict__ out,
                                              const int* __restrict__ flag) {
  const bool f32in = (*flag != 0);
  size_t i = ((size_t)blockIdx.x * 256 + threadIdx.x) * 8;
  const size_t stride = (size_t)gridDim.x * 256 * 8;
  for (; i < MSD; i += stride) {
    if (f32in) {
      const float4 a = ((const float4*)in)[i/4];
      const float4 b = ((const float4*)in)[i/4 + 1];
      uint4 o; unsigned short* po = (unsigned short*)&o;
      po[0]=f2bu(a.x); po[1]=f2bu(a.y); po[2]=f2bu(a.z); po[3]=f2bu(a.w);
      po[4]=f2bu(b.x); po[5]=f2bu(b.y); po[6]=f2bu(b.z); po[7]=f2bu(b.w);
      *(uint4*)((unsigned short*)out + i) = o;
    } else {
      *(uint4*)((unsigned short*)out + i) = *(const uint4*)((const unsigned short*)in + i);
    }
  }
}

// ---------------- merged weight/bias/gamma convert with zero-padding ----------------
struct Seg { const void* src; void* dst; int srcRows, srcK, dstK, total; };
struct Segs { Seg s[16]; unsigned int isbf; };

__global__ __launch_bounds__(256) void cvt_all(Segs sg, const int* __restrict__ flag) {
  const bool f32in = (*flag != 0);
  const int seg = blockIdx.x & 15;
  const Seg sd = sg.s[seg];
  const int stride = (gridDim.x >> 4) * 256;
  const bool nopad = (sd.srcK == sd.dstK);
  for (int i = (blockIdx.x >> 4) * 256 + threadIdx.x; i < sd.total; i += stride) {
    int sidx; bool valid;
    if (nopad) { sidx = i; valid = (i < sd.srcRows * sd.srcK); }
    else {
      int r = i / sd.dstK, c = i - r * sd.dstK;
      valid = (r < sd.srcRows) && (c < sd.srcK);
      sidx = r * sd.srcK + c;
    }
    float v = 0.f;
    if (valid) v = f32in ? ((const float*)sd.src)[sidx] : b2f(((const bf16*)sd.src)[sidx]);
    if (sg.isbf & (1u << seg)) ((unsigned short*)sd.dst)[i] = f2bu(v);
    else                       ((float*)sd.dst)[i] = v;
  }
}

// ---------------- gamma/beta global constants: CG, CG2, CGB, CB, CB2 ----------------
// Reads the CONVERTED bf16 gm/bt (2MB); 64 blocks x 256 thr x 4 us4-groups each.
__global__ __launch_bounds__(256) void gb_stats(const bf16* __restrict__ g,
    const bf16* __restrict__ b, float* __restrict__ cst) {
  __shared__ float red[5][256];
  const int tid = threadIdx.x;
  float c0=0.f, c1=0.f, c2=0.f, c3=0.f, c4=0.f;
#pragma unroll
  for (int k = 0; k < 4; k++) {
    const int grp = blockIdx.x*256 + tid + k*16384;   // us4 group id, 65536 total
    us4 g4 = *(const us4*)((const unsigned short*)g + grp*4);
    us4 b4 = *(const us4*)((const unsigned short*)b + grp*4);
#pragma unroll
    for (int j = 0; j < 4; j++) {
      float G = bu2f(g4[j]), B = bu2f(b4[j]);
      c0 += G; c1 += G*G; c2 += G*B; c3 += B; c4 += B*B;
    }
  }
  red[0][tid]=c0; red[1][tid]=c1; red[2][tid]=c2; red[3][tid]=c3; red[4][tid]=c4;
  __syncthreads();
  for (int st = 128; st; st >>= 1) {
    if (tid < st)
#pragma unroll
      for (int q = 0; q < 5; q++) red[q][tid] += red[q][tid + st];
    __syncthreads();
  }
  if (tid == 0)
#pragma unroll
    for (int q = 0; q < 5; q++) atomicAdd(&cst[q], red[q][0]);
}

// ---------------- bf16 MFMA GEMM: 3-plane pipeline, SINGLE barrier per K-step --------
// C[m,n] = sum_k A[m,k]*W[n,k] + bias[n].  Requires M%128==0, N%128==0, K%32==0, K>=96.
// MODE: 0=plain, 1=relu, 2=+residual R(bf16)
// STATS: 0=none; 1=per-batch sum/sumsq -> stats[b*2(+1)];
//        2=extended LN23 stats (requires N==512): per-batch
//        {Sv, Svv, SGv, SG2v, SG2v2, SGBv} -> stats[b*6..], gamma/beta from gmp/btp.
// Grid is (M/128, N/128) M-fast: blocks sharing an A-panel land on the SAME XCD.
// R8's proven form. R9 4-plane regressed (occupancy 24.5->16.6%): K-loop is
// LDS-BW-bound at this tile -> deeper prefetch cannot help.
template<int MODE, int STATS>
__global__ __launch_bounds__(256) void gemm_mfma(
    const bf16* __restrict__ A, const bf16* __restrict__ W, const float* __restrict__ bias,
    const bf16* __restrict__ R, bf16* __restrict__ C, int M, int N, int K,
    float* __restrict__ stats, const bf16* __restrict__ gmp, const bf16* __restrict__ btp)
{
  __shared__ __align__(16) char smem[49152];
  bf16*  As  = (bf16*)smem;                 // [3][128][32]  24 KB
  bf16*  Bs  = (bf16*)(smem + 24576);       // [3][128][32]  24 KB
  float* Lf  = (float*)smem;                // [32][132] fp32 epilogue staging (16896 B)
  float* red = (float*)(smem + 16896);      // up to 6*256 floats stats reduction

  const int tid  = threadIdx.x;
  const int bm   = blockIdx.x * 128;
  const int bn   = blockIdx.y * 128;
  const int w    = tid >> 6;
  const int lane = tid & 63;
  const int qd   = lane >> 4;
  const int ln   = lane & 15;
  const int wr   = (w >> 1) * 64;
  const int wc   = (w & 1) * 64;

  const int r0 = lane >> 2;
  const int ch = (lane & 3) * 8;
  const bf16* Ag0 = A + (size_t)(bm + w*16 + r0) * K + ch;
  const bf16* Ag1 = Ag0 + (size_t)64 * K;
  const bf16* Bg0 = W + (size_t)(bn + w*16 + r0) * K + ch;
  const bf16* Bg1 = Bg0 + (size_t)64 * K;
  const int lo = w*512 + lane*8;            // offset within a 4096-elem plane

  f32x4 acc[4][4] = {};
  const int nt = K >> 5;

  // prologue: stage tiles 0,1 into planes 0,1
  async16(Ag0, As + lo);
  async16(Ag1, As + lo + 2048);
  async16(Bg0, Bs + lo);
  async16(Bg1, Bs + lo + 2048);
  async16(Ag0 + 32, As + 4096 + lo);
  async16(Ag1 + 32, As + 4096 + lo + 2048);
  async16(Bg0 + 32, Bs + 4096 + lo);
  async16(Bg1 + 32, Bs + 4096 + lo + 2048);

  int pcur = 0;                              // plane holding tile t
  for (int t = 0; t < nt; t++) {
    if (t + 1 < nt) {
      asm volatile("s_waitcnt vmcnt(4)" ::: "memory");   // tile-t landed; t+1 in flight
    } else {
      asm volatile("s_waitcnt vmcnt(0)" ::: "memory");
    }
    __builtin_amdgcn_s_barrier();                        // tile t visible to all waves

    const int cur = pcur << 12;
    short8 af[4], bfr[4];
#pragma unroll
    for (int i = 0; i < 4; i++) af[i]  = *(const short8*)(As + cur + (wr + i*16 + ln)*32 + qd*8);
#pragma unroll
    for (int j = 0; j < 4; j++) bfr[j] = *(const short8*)(Bs + cur + (wc + j*16 + ln)*32 + qd*8);

    if (t + 2 < nt) {
      int pst = pcur - 1; if (pst < 0) pst = 2;   // (pcur+2)%3
      const int nxt = pst << 12;
      const int k0  = (t + 2) << 5;
      async16(Ag0 + k0, As + nxt + lo);
      async16(Ag1 + k0, As + nxt + lo + 2048);
      async16(Bg0 + k0, Bs + nxt + lo);
      async16(Bg1 + k0, Bs + nxt + lo + 2048);
    }

#pragma unroll
    for (int i = 0; i < 4; i++)
#pragma unroll
      for (int j = 0; j < 4; j++)
        acc[i][j] = __builtin_amdgcn_mfma_f32_16x16x32_bf16(af[i], bfr[j], acc[i][j], 0, 0, 0);

    pcur = pcur + 1 == 3 ? 0 : pcur + 1;
  }
  __syncthreads();                           // all reads done before Lf aliases planes

  // ---- epilogue: 4 chunks of 32 rows; stage fp32 in LDS, readback coalesced ----
  float s_acc = 0.f, ss_acc = 0.f;
  float a2 = 0.f, a3 = 0.f, a4 = 0.f, a5 = 0.f;   // STATS==2 weighted sums
  const int lrbase = (w >> 1)*16 + qd*4;
#pragma unroll
  for (int i = 0; i < 4; i++) {
#pragma unroll
    for (int j = 0; j < 4; j++) {
      const int col = wc + j*16 + ln;
#pragma unroll
      for (int rg = 0; rg < 4; rg++)
        Lf[(lrbase + rg)*132 + col] = acc[i][j][rg];
    }
    __syncthreads();
    // readback: 2 pairs of float4 per thread -> one 16B bf16 store each
#pragma unroll
    for (int pz = 0; pz < 2; pz++) {
      const int q   = tid + pz*256;
      const int r   = q >> 4;            // 0..31
      const int nof = (q & 15)*8;        // 0..120
      const int m   = bm + (r >> 4)*64 + i*16 + (r & 15);
      const int n   = bn + nof;
      f32x4 v0 = *(const f32x4*)(Lf + r*132 + nof);
      f32x4 v1 = *(const f32x4*)(Lf + r*132 + nof + 4);
      f32x4 b0 = *(const f32x4*)(bias + n);
      f32x4 b1 = *(const f32x4*)(bias + n + 4);
      float vals[8];
#pragma unroll
      for (int e = 0; e < 4; e++) { vals[e] = v0[e] + b0[e]; vals[4+e] = v1[e] + b1[e]; }
      if (MODE == 1) {
#pragma unroll
        for (int e = 0; e < 8; e++) vals[e] = fmaxf(vals[e], 0.f);
      }
      if (MODE == 2) {
        const uint4 rv = *(const uint4*)((const unsigned short*)R + (size_t)m * N + n);
        const unsigned short* rp = (const unsigned short*)&rv;
#pragma unroll
        for (int e = 0; e < 8; e++) vals[e] += bu2f(rp[e]);
      }
      if (STATS == 1) {
#pragma unroll
        for (int e = 0; e < 8; e++) { s_acc += vals[e]; ss_acc += vals[e]*vals[e]; }
      }
      if (STATS == 2) {
        const int ei = ((m & 511) << 9) + n;     // N==512 layout
        const uint4 gv = *(const uint4*)((const unsigned short*)gmp + ei);
        const uint4 bv = *(const uint4*)((const unsigned short*)btp + ei);
        const unsigned short* gp = (const unsigned short*)&gv;
        const unsigned short* bp = (const unsigned short*)&bv;
#pragma unroll
        for (int e = 0; e < 8; e++) {
          const float vv = vals[e];
          const float G  = bu2f(gp[e]);
          const float Bv = bu2f(bp[e]);
          s_acc += vv; ss_acc += vv*vv;
          a2 += G*vv; a3 += G*G*vv; a4 += G*G*vv*vv; a5 += G*Bv*vv;
        }
      }
      uint4 o; unsigned short* op = (unsigned short*)&o;
#pragma unroll
      for (int e = 0; e < 8; e++) op[e] = f2bu(vals[e]);
      *(uint4*)((unsigned short*)C + (size_t)m * N + n) = o;
    }
    __syncthreads();
  }

  if (STATS == 1) {
    red[tid] = s_acc; red[256 + tid] = ss_acc;
    __syncthreads();
    for (int st = 128; st; st >>= 1) {
      if (tid < st) { red[tid] += red[tid + st]; red[256 + tid] += red[256 + tid + st]; }
      __syncthreads();
    }
    if (tid == 0) {
      const int b = bm >> 9;
      atomicAdd(&stats[b*2],     red[0]);
      atomicAdd(&stats[b*2 + 1], red[256]);
    }
  }
  if (STATS == 2) {
    float v6[6] = { s_acc, ss_acc, a2, a3, a4, a5 };
#pragma unroll
    for (int q2 = 0; q2 < 6; q2++) red[q2*256 + tid] = v6[q2];
    __syncthreads();
    for (int st = 128; st; st >>= 1) {
      if (tid < st)
#pragma unroll
        for (int q2 = 0; q2 < 6; q2++) red[q2*256 + tid] += red[q2*256 + tid + st];
      __syncthreads();
    }
    if (tid == 0) {
      const int b = bm >> 9;
#pragma unroll
      for (int q2 = 0; q2 < 6; q2++) atomicAdd(&stats[b*6 + q2], red[q2*256]);
    }
  }
}

// ---------------- attention: chunked K/V staging overlapped with compute (T14) -------
// qkv: [M][1536] = [b*512+s][q(512)|k(512)|v(512)], head h at columns h*64.
// One block per (b,h); 16 waves; each wave does 32 queries x 512 keys.
// Keys split in 2 chunks of 256; chunk-1 staged during chunk-0 compute with counted
// waits + raw barrier. R10's 4-chunk variant spilled (VGPR 64 + 200MB scratch):
// 2 chunks is the codegen-safe depth.
__global__ __launch_bounds__(1024, 4) void attn_lds(const bf16* __restrict__ qkv,
                                                    bf16* __restrict__ cat)
{
  __shared__ bf16 Ks[2 * 512 * 32];     // 64 KB [ks][key][32]
  __shared__ bf16 Vs[64 * 520];         // 65 KB [dk][key] padded
  __shared__ bf16 pbuf[16][16][40];     // 20 KB per-wave prob staging

  const int tid  = threadIdx.x;
  const int w    = tid >> 6;
  const int lane = tid & 63;
  const int qd   = lane >> 4;
  const int ln   = lane & 15;
  const int bh   = blockIdx.x;
  const int b    = bh >> 3, h = bh & 7;
  const bf16* base = qkv + (size_t)b * 512 * NQKV + h * 64;

  // --- stage K chunk 0 (keys 0..255): [ks][key][32] layout ---
#pragma unroll
  for (int r = 0; r < 2; r++) {
    int c = tid + r*1024;                       // [0,2048)
    int part = c & 3, key = (c >> 2) & 255, ks = c >> 10;
    async16(base + (size_t)key * NQKV + 512 + ks*32 + part*8,
            Ks + ks*16384 + key*32 + part*8);
  }
  // --- stage V chunk 0 transposed: Vs[dk][key], conflict-free lane<->key mapping ---
#pragma unroll
  for (int r = 0; r < 2; r++) {
    int c = tid + r*1024;
    int dkg = c >> 8, key = c & 255;
    uint4 vv = *(const uint4*)(base + (size_t)key * NQKV + 1024 + dkg*8);
    const unsigned short* pv = (const unsigned short*)&vv;
#pragma unroll
    for (int j = 0; j < 8; j++)
      *(unsigned short*)&Vs[(dkg*8 + j)*520 + key] = pv[j];
  }
  // --- Q B-frags for this wave's 32 queries ---
  short8 bq[2][2];
#pragma unroll
  for (int qt = 0; qt < 2; qt++)
#pragma unroll
    for (int ks = 0; ks < 2; ks++)
      bq[qt][ks] = *(const short8*)(base + (size_t)(w*32 + qt*16 + ln) * NQKV + ks*32 + qd*8);

  __syncthreads();                              // chunk 0 visible

  // --- issue chunk 1 staging (keys 256..511): K direct-to-LDS, V into registers ---
#pragma unroll
  for (int r = 0; r < 2; r++) {
    int c = tid + r*1024;
    int part = c & 3, key = 256 + ((c >> 2) & 255), ks = c >> 10;
    async16(base + (size_t)key * NQKV + 512 + ks*32 + part*8,
            Ks + ks*16384 + key*32 + part*8);
  }
  uint4 vhold[2]; int vdst[2];
#pragma unroll
  for (int r = 0; r < 2; r++) {
    int c = tid + r*1024;
    int dkg = c >> 8, key = 256 + (c & 255);
    vhold[r] = *(const uint4*)(base + (size_t)key * NQKV + 1024 + dkg*8);
    vdst[r] = dkg*8*520 + key;
  }
  asm volatile("" ::: "memory");                // pin load issue before compute

  bf16 (*pb)[40] = pbuf[w];
  f32x4 o[2][4] = {};
  float l[2] = {0.f, 0.f};

  for (int half = 0; half < 2; half++) {
    for (int st = half*8; st < half*8 + 8; st++) {
      short8 ak[2][2];
#pragma unroll
      for (int kt = 0; kt < 2; kt++)
#pragma unroll
        for (int ks = 0; ks < 2; ks++)
          ak[kt][ks] = *(const short8*)(Ks + ks*16384 + (st*32 + kt*16 + ln)*32 + qd*8);
      f32x4 s[2][2] = {};
#pragma unroll
      for (int kt = 0; kt < 2; kt++)
#pragma unroll
        for (int qt = 0; qt < 2; qt++) {
          s[kt][qt] = __builtin_amdgcn_mfma_f32_16x16x32_bf16(ak[kt][0], bq[qt][0], s[kt][qt], 0, 0, 0);
          s[kt][qt] = __builtin_amdgcn_mfma_f32_16x16x32_bf16(ak[kt][1], bq[qt][1], s[kt][qt], 0, 0, 0);
        }
      float e[2][2][4];
#pragma unroll
      for (int kt = 0; kt < 2; kt++)
#pragma unroll
        for (int qt = 0; qt < 2; qt++)
#pragma unroll
          for (int rg = 0; rg < 4; rg++) {
            float ev = __expf(s[kt][qt][rg] * 0.125f);
            e[kt][qt][rg] = ev;
            l[qt] += ev;
          }
#pragma unroll
      for (int qt = 0; qt < 2; qt++) {
#pragma unroll
        for (int kt = 0; kt < 2; kt++) {
          uint2 pk;
          pk.x = (unsigned)f2bu(e[kt][qt][0]) | ((unsigned)f2bu(e[kt][qt][1]) << 16);
          pk.y = (unsigned)f2bu(e[kt][qt][2]) | ((unsigned)f2bu(e[kt][qt][3]) << 16);
          *(uint2*)&pb[ln][kt*16 + qd*4] = pk;
        }
        short8 ap = *(const short8*)&pb[ln][qd*8];
#pragma unroll
        for (int nt = 0; nt < 4; nt++) {
          short8 bv = *(const short8*)(Vs + (nt*16 + ln)*520 + st*32 + qd*8);
          o[qt][nt] = __builtin_amdgcn_mfma_f32_16x16x32_bf16(ap, bv, o[qt][nt], 0, 0, 0);
        }
      }
    }
    if (half == 0) {
      // land chunk 1: V regs -> LDS (K async16 already targeted LDS directly)
      asm volatile("s_waitcnt vmcnt(0)" ::: "memory");
#pragma unroll
      for (int r = 0; r < 2; r++) {
        const unsigned short* pv = (const unsigned short*)&vhold[r];
#pragma unroll
        for (int j = 0; j < 8; j++)
          *(unsigned short*)&Vs[vdst[r] + j*520] = pv[j];
      }
      asm volatile("s_waitcnt lgkmcnt(0)" ::: "memory");
      __builtin_amdgcn_s_barrier();             // chunk 1 visible to all waves
    }
  }

#pragma unroll
  for (int qt = 0; qt < 2; qt++) {
    l[qt] += __shfl_xor(l[qt], 16);
    l[qt] += __shfl_xor(l[qt], 32);
  }
  float inv0 = 1.f / l[0], inv1 = 1.f / l[1];

  const size_t crow0 = (size_t)(b*S_ + w*32) * D_ + h*DK_;
#pragma unroll
  for (int qt = 0; qt < 2; qt++) {
#pragma unroll
    for (int rg = 0; rg < 4; rg++) {
      float ivv = __shfl(qt ? inv1 : inv0, qd*4 + rg);
      int r = qt*16 + qd*4 + rg;
      bf16* cp = cat + crow0 + (size_t)r * D_ + ln;
#pragma unroll
      for (int nt = 0; nt < 4; nt++) cp[nt*16] = f2b(o[qt][nt][rg] * ivv);
    }
  }
}

// ---------------- LN1 apply (bf16 in/out), stats precomputed, bf16 gamma/beta --------
__global__ __launch_bounds__(256) void ln_b16_b16(const bf16* __restrict__ in,
    const float* __restrict__ stats, const bf16* __restrict__ gamma,
    const bf16* __restrict__ beta, bf16* __restrict__ out)
{
  const int b = blockIdx.x >> 4;
  const float invN = 1.f / (float)(S_*D_);
  const float m    = stats[b*2] * invN;
  const float var  = stats[b*2+1] * invN - m*m;
  const float rstd = rsqrtf(var + 1e-5f);
  size_t v = (size_t)b * 65536 + (blockIdx.x & 15) * 4096 + threadIdx.x;
#pragma unroll 4
  for (int it = 0; it < 16; it++, v += 256) {
    us4 xi = *(const us4*)((const unsigned short*)in + v*4);
    size_t e = (v * 4) & (S_*D_ - 1);
    us4 g4 = *(const us4*)((const unsigned short*)gamma + e);
    us4 b4 = *(const us4*)((const unsigned short*)beta + e);
    us4 o;
    o[0] = f2bu((bu2f(xi[0]) - m) * rstd * bu2f(g4[0]) + bu2f(b4[0]));
    o[1] = f2bu((bu2f(xi[1]) - m) * rstd * bu2f(g4[1]) + bu2f(b4[1]));
    o[2] = f2bu((bu2f(xi[2]) - m) * rstd * bu2f(g4[2]) + bu2f(b4[2]));
    o[3] = f2bu((bu2f(xi[3]) - m) * rstd * bu2f(g4[3]) + bu2f(b4[3]));
    *(us4*)((unsigned short*)out + v*4) = o;
  }
}

// ---------------- fused LN2+LN3: single pass yB -> out -------------------------------
// LN2 params (m2,r2) from extended stats {Sv,Svv}; LN3 params derived ALGEBRAICALLY:
//   Sy  = r2*(SGv - m2*CG) + CB
//   SSy = r2^2*(SG2v2 - 2*m2*SG2v + m2^2*CG2) + 2*r2*(SGBv - m2*CGB) + CB2
// where y2 = (v-m2)*r2*g + b; out = (y2-m3)*r3*g + b. Eliminates the y2 pass.
__global__ __launch_bounds__(256) void ln23_fused(const bf16* __restrict__ in,
    const float* __restrict__ st2x, const float* __restrict__ cst,
    const bf16* __restrict__ gamma, const bf16* __restrict__ beta,
    void* __restrict__ out, const int* __restrict__ flag)
{
  const bool f32 = (*flag != 0);
  const int b = blockIdx.x >> 4;
  const float invN = 1.f / (float)(S_*D_);
  const float Sv   = st2x[b*6+0], Svv  = st2x[b*6+1];
  const float SGv  = st2x[b*6+2], SG2v = st2x[b*6+3];
  const float SG2v2= st2x[b*6+4], SGBv = st2x[b*6+5];
  const float CG = cst[0], CG2 = cst[1], CGB = cst[2], CB = cst[3], CB2 = cst[4];
  const float m2 = Sv * invN;
  const float r2 = rsqrtf(Svv * invN - m2*m2 + 1e-5f);
  const float Sy  = r2 * (SGv - m2*CG) + CB;
  const float SSy = r2*r2 * (SG2v2 - 2.f*m2*SG2v + m2*m2*CG2)
                  + 2.f*r2 * (SGBv - m2*CGB) + CB2;
  const float m3 = Sy * invN;
  const float r3 = rsqrtf(SSy * invN - m3*m3 + 1e-5f);

  size_t v = (size_t)b * 65536 + (blockIdx.x & 15) * 4096 + threadIdx.x;
#pragma unroll 4
  for (int it = 0; it < 16; it++, v += 256) {
    us4 xi = *(const us4*)((const unsigned short*)in + v*4);
    size_t e = (v * 4) & (S_*D_ - 1);
    us4 g4 = *(const us4*)((const unsigned short*)gamma + e);
    us4 b4 = *(const us4*)((const unsigned short*)beta + e);
    float4 o;
    {
      float G = bu2f(g4[0]), B = bu2f(b4[0]);
      float y2 = (bu2f(xi[0]) - m2) * r2 * G + B;
      o.x = (y2 - m3) * r3 * G + B;
    }
    {
      float G = bu2f(g4[1]), B = bu2f(b4[1]);
      float y2 = (bu2f(xi[1]) - m2) * r2 * G + B;
      o.y = (y2 - m3) * r3 * G + B;
    }
    {
      float G = bu2f(g4[2]), B = bu2f(b4[2]);
      float y2 = (bu2f(xi[2]) - m2) * r2 * G + B;
      o.z = (y2 - m3) * r3 * G + B;
    }
    {
      float G = bu2f(g4[3]), B = bu2f(b4[3]);
      float y2 = (bu2f(xi[3]) - m2) * r2 * G + B;
      o.w = (y2 - m3) * r3 * G + B;
    }
    if (f32) ((float4*)out)[v] = o;
    else {
      us4 ob;
      ob[0] = f2bu(o.x); ob[1] = f2bu(o.y); ob[2] = f2bu(o.z); ob[3] = f2bu(o.w);
      *(us4*)((unsigned short*)out + v*4) = ob;
    }
  }
}

// ---------------- launch ----------------
extern "C" void kernel_launch(void* const* d_in, const int* in_sizes, int n_in,
                              void* d_out, int out_size, void* d_ws, size_t ws_size,
                              hipStream_t stream)
{
  char* p = (char*)d_ws;
  auto alloc_b = [&](size_t elems) { void* r = p; p += elems * 2; return (bf16*)r; };
  auto alloc_f = [&](size_t elems) {
    p = (char*)(((uintptr_t)p + 15) & ~(uintptr_t)15); void* r = p; p += elems * 4; return (float*)r;
  };

  bf16* xb   = alloc_b(MSD);            // x bf16
  bf16* qkv  = alloc_b(3 * MSD);        // [M][1536] natural
  bf16* catb = alloc_b(MSD);
  bf16* wqkv = alloc_b(3 * 512 * 512);
  bf16* wo   = alloc_b(512 * 512);
  bf16* w1p  = alloc_b((size_t)FFP * 512);
  bf16* w2p  = alloc_b((size_t)FFP * FFP);
  bf16* w3p  = alloc_b((size_t)512 * FFP);
  bf16* gm   = alloc_b((size_t)S_ * D_);   // gamma bf16
  bf16* bt   = alloc_b((size_t)S_ * D_);   // beta  bf16
  float* bqkv= alloc_f(3 * 512);
  float* bo  = alloc_f(512);
  float* b1p = alloc_f(FFP);
  float* b2p = alloc_f(FFP);
  float* b3  = alloc_f(512);
  float* stats = alloc_f(320);          // st1(64) | cst(16) | st2x(192) | pad
  int*   flag  = (int*)alloc_f(16);
  if ((size_t)(p - (char*)d_ws) > ws_size) return;

  // intermediates aliased into dead regions:
  bf16* y1b = qkv;                      // LN1 out [M][512]   (qkv dead after attn)
  bf16* f1  = qkv + MSD;                // [M][FFP]
  bf16* f2  = qkv + MSD + (size_t)M_ * FFP;
  bf16* yA  = qkv + 2 * MSD;            // out-proj + residual (bf16)
  bf16* yB  = catb;                     // FFN3 + residual     (catb dead after out-proj)
  float* st1  = stats;                  // LN1 stats, 2/batch
  float* cst  = stats + 64;             // gamma/beta consts: CG,CG2,CGB,CB,CB2
  float* st2x = stats + 80;             // extended LN23 stats, 6/batch

  detect_kernel<<<1, 256, 0, stream>>>((const unsigned short*)d_in[0], flag, stats);
  cvt_x8<<<2048, 256, 0, stream>>>(d_in[0], xb, flag);

  Segs sg;
  // {src, dst, srcRows, srcK, dstK, total}
  sg.s[0]  = { d_in[1],  wqkv,               512, 512, 512, 512*512 };
  sg.s[1]  = { d_in[3],  wqkv + 512*512,     512, 512, 512, 512*512 };
  sg.s[2]  = { d_in[5],  wqkv + 2*512*512,   512, 512, 512, 512*512 };
  sg.s[3]  = { d_in[7],  wo,                 512, 512, 512, 512*512 };
  sg.s[4]  = { d_in[9],  w1p,                FF_, 512, 512, FFP*512 };
  sg.s[5]  = { d_in[11], w2p,                FF_, FF_, FFP, FFP*FFP };
  sg.s[6]  = { d_in[13], w3p,                512, FF_, FFP, 512*FFP };
  sg.s[7]  = { d_in[2],  bqkv,               1, 512, 512, 512 };
  sg.s[8]  = { d_in[4],  bqkv + 512,         1, 512, 512, 512 };
  sg.s[9]  = { d_in[6],  bqkv + 1024,        1, 512, 512, 512 };
  sg.s[10] = { d_in[8],  bo,                 1, 512, 512, 512 };
  sg.s[11] = { d_in[10], b1p,                1, FF_, FFP, FFP };
  sg.s[12] = { d_in[12], b2p,                1, FF_, FFP, FFP };
  sg.s[13] = { d_in[14], b3,                 1, 512, 512, 512 };
  sg.s[14] = { d_in[15], gm,                 1, S_*D_, S_*D_, S_*D_ };
  sg.s[15] = { d_in[16], bt,                 1, S_*D_, S_*D_, S_*D_ };
  sg.isbf = 0xC07F;                     // weights + gamma/beta are bf16
  cvt_all<<<1024, 256, 0, stream>>>(sg, flag);

  // gamma/beta global constants for the LN23 fusion (reads converted bf16 gm/bt)
  gb_stats<<<64, 256, 0, stream>>>(gm, bt, cst);

  dim3 blk(256);

  // fused QKV projection: plain GEMM, natural output [M][1536]
  gemm_mfma<0, 0><<<dim3(M_/128, NQKV/128), blk, 0, stream>>>(
      xb, wqkv, bqkv, nullptr, qkv, M_, NQKV, 512, nullptr, nullptr, nullptr);

  attn_lds<<<B_*H_, 1024, 0, stream>>>(qkv, catb);

  // output projection + residual x -> bf16 yA, fused LN1 stats
  gemm_mfma<2, 1><<<dim3(M_/128, 4), blk, 0, stream>>>(
      catb, wo, bo, xb, yA, M_, 512, 512, st1, nullptr, nullptr);

  ln_b16_b16<<<512, blk, 0, stream>>>(yA, st1, gm, bt, y1b);

  // FFN (padded to 256)
  gemm_mfma<1, 0><<<dim3(M_/128, 2), blk, 0, stream>>>(
      y1b, w1p, b1p, nullptr, f1, M_, FFP, 512, nullptr, nullptr, nullptr);
  gemm_mfma<1, 0><<<dim3(M_/128, 2), blk, 0, stream>>>(
      f1, w2p, b2p, nullptr, f2, M_, FFP, FFP, nullptr, nullptr, nullptr);
  // FFN3 + residual -> yB, with EXTENDED stats for the LN2+LN3 fusion
  gemm_mfma<2, 2><<<dim3(M_/128, 4), blk, 0, stream>>>(
      f2, w3p, b3, y1b, yB, M_, 512, FFP, st2x, gm, bt);

  // fused LN2-apply + LN3 (stats derived algebraically) -> out, single pass
  ln23_fused<<<512, blk, 0, stream>>>(yB, st2x, cst, gm, bt, d_out, flag);
}

// Round 13
// 263.419 us; speedup vs baseline: 1.5602x; 1.0370x over previous
//
#include <hip/hip_runtime.h>
#include <hip/hip_bf16.h>
#include <stdint.h>

// encoder_layer: B=32,S=512,D=512,H=8,DK=64,FF=200. bf16 MFMA, fp32 LN stats.
#define B_  32
#define S_  512
#define D_  512
#define H_  8
#define DK_ 64
#define FF_ 200
#define FFP 256                 // FF padded to 256 (zero-fill) -> unguarded GEMMs
#define M_  (B_*S_)             // 16384
#define MSD ((size_t)B_*S_*D_)  // 8388608
#define NQKV 1536

typedef __hip_bfloat16 bf16;
typedef __attribute__((ext_vector_type(8))) short short8;
typedef __attribute__((ext_vector_type(4))) float f32x4;
typedef __attribute__((ext_vector_type(4))) unsigned short us4;

__device__ inline float b2f(bf16 v) { return __bfloat162float(v); }
__device__ inline bf16  f2b(float v){ return __float2bfloat16(v); }
__device__ inline unsigned short f2bu(float v) {
  union { bf16 h; unsigned short u; } cv; cv.h = __float2bfloat16(v); return cv.u;
}
__device__ inline float bu2f(unsigned short u) {
  union { unsigned short u; bf16 h; } cv; cv.u = u; return b2f(cv.h);
}
__device__ __forceinline__ void async16(const bf16* g, bf16* l) {
  __builtin_amdgcn_global_load_lds((const __attribute__((address_space(1))) void*)g,
                                   (__attribute__((address_space(3))) void*)l, 16, 0, 0);
}

// ---------------- dtype detection (flag=1 -> fp32 inputs) + stats zero ----------------
__global__ void detect_kernel(const unsigned short* __restrict__ xu, int* __restrict__ flag,
                              float* __restrict__ stats) {
  __shared__ int mx[256];
  const int tid = threadIdx.x;
  if (tid < 160) { stats[tid] = 0.f; stats[tid + 160] = 0.f; }   // zero 320 floats
  int m = 0;
  for (int i = tid * 2; i < 8192; i += 512) {
    int e = (xu[i] >> 7) & 0xFF;
    m = m > e ? m : e;
  }
  mx[tid] = m;
  __syncthreads();
  for (int st = 128; st; st >>= 1) {
    if (tid < st) mx[tid] = mx[tid] > mx[tid + st] ? mx[tid] : mx[tid + st];
    __syncthreads();
  }
  if (tid == 0) *flag = (mx[0] >= 0xC0) ? 1 : 0;
}

// ---------------- merged weight/bias/gamma convert with zero-padding ----------------
struct Seg { const void* src; void* dst; int srcRows, srcK, dstK, total; };
struct Segs { Seg s[16]; unsigned int isbf; };

// ---------------- fused front-end: x-convert + seg-convert + gamma/beta constants ----
// One launch, 3 block roles (all independent given flag from detect_kernel):
//   bid <  2048: x convert, 8 elems/thread (bf16 copy or f32->bf16)
//   bid <  3072: weight/bias/gamma convert with zero-padding (seg = (bid-2048)&15)
//   bid >= 3072: gamma/beta constants CG,CG2,CGB,CB,CB2 from RAW inputs with the
//                identical f2bu rounding -> bit-identical to reading converted gm/bt.
// The two small roles hide entirely under the BW-bound x-convert; saves 2 launch gaps.
__global__ __launch_bounds__(256) void cvt_fused(const void* __restrict__ xin,
    bf16* __restrict__ xout, Segs sg, const int* __restrict__ flag,
    const void* __restrict__ gsrc, const void* __restrict__ bsrc,
    float* __restrict__ cst)
{
  const bool f32in = (*flag != 0);
  const int bid = blockIdx.x;
  const int tid = threadIdx.x;

  if (bid < 2048) {
    // ---- x convert ----
    size_t i = ((size_t)bid * 256 + tid) * 8;
    const size_t stride = (size_t)2048 * 256 * 8;
    for (; i < MSD; i += stride) {
      if (f32in) {
        const float4 a = ((const float4*)xin)[i/4];
        const float4 b = ((const float4*)xin)[i/4 + 1];
        uint4 o; unsigned short* po = (unsigned short*)&o;
        po[0]=f2bu(a.x); po[1]=f2bu(a.y); po[2]=f2bu(a.z); po[3]=f2bu(a.w);
        po[4]=f2bu(b.x); po[5]=f2bu(b.y); po[6]=f2bu(b.z); po[7]=f2bu(b.w);
        *(uint4*)((unsigned short*)xout + i) = o;
      } else {
        *(uint4*)((unsigned short*)xout + i) = *(const uint4*)((const unsigned short*)xin + i);
      }
    }
  } else if (bid < 3072) {
    // ---- seg convert ----
    const int b2  = bid - 2048;
    const int seg = b2 & 15;
    const Seg sd = sg.s[seg];
    const int stride = 64 * 256;                 // 1024/16 blocks per seg
    const bool nopad = (sd.srcK == sd.dstK);
    for (int i = (b2 >> 4) * 256 + tid; i < sd.total; i += stride) {
      int sidx; bool valid;
      if (nopad) { sidx = i; valid = (i < sd.srcRows * sd.srcK); }
      else {
        int r = i / sd.dstK, c = i - r * sd.dstK;
        valid = (r < sd.srcRows) && (c < sd.srcK);
        sidx = r * sd.srcK + c;
      }
      float v = 0.f;
      if (valid) v = f32in ? ((const float*)sd.src)[sidx] : b2f(((const bf16*)sd.src)[sidx]);
      if (sg.isbf & (1u << seg)) ((unsigned short*)sd.dst)[i] = f2bu(v);
      else                       ((float*)sd.dst)[i] = v;
    }
  } else {
    // ---- gamma/beta constants (bf16-rounded, from raw inputs) ----
    __shared__ float red[5][256];
    const int b3 = bid - 3072;                   // [0,64)
    float c0=0.f, c1=0.f, c2=0.f, c3=0.f, c4=0.f;
#pragma unroll
    for (int k = 0; k < 4; k++) {
      const int grp = b3*256 + tid + k*16384;    // us4/float4 group id, 65536 total
      float G[4], Bv[4];
      if (f32in) {
        float4 ga = ((const float4*)gsrc)[grp];
        float4 ba = ((const float4*)bsrc)[grp];
        G[0]=bu2f(f2bu(ga.x)); G[1]=bu2f(f2bu(ga.y)); G[2]=bu2f(f2bu(ga.z)); G[3]=bu2f(f2bu(ga.w));
        Bv[0]=bu2f(f2bu(ba.x)); Bv[1]=bu2f(f2bu(ba.y)); Bv[2]=bu2f(f2bu(ba.z)); Bv[3]=bu2f(f2bu(ba.w));
      } else {
        us4 g4 = *(const us4*)((const unsigned short*)gsrc + grp*4);
        us4 b4 = *(const us4*)((const unsigned short*)bsrc + grp*4);
#pragma unroll
        for (int j = 0; j < 4; j++) { G[j] = bu2f(g4[j]); Bv[j] = bu2f(b4[j]); }
      }
#pragma unroll
      for (int j = 0; j < 4; j++) {
        c0 += G[j]; c1 += G[j]*G[j]; c2 += G[j]*Bv[j]; c3 += Bv[j]; c4 += Bv[j]*Bv[j];
      }
    }
    red[0][tid]=c0; red[1][tid]=c1; red[2][tid]=c2; red[3][tid]=c3; red[4][tid]=c4;
    __syncthreads();
    for (int st = 128; st; st >>= 1) {
      if (tid < st)
#pragma unroll
        for (int q = 0; q < 5; q++) red[q][tid] += red[q][tid + st];
      __syncthreads();
    }
    if (tid == 0)
#pragma unroll
      for (int q = 0; q < 5; q++) atomicAdd(&cst[q], red[q][0]);
  }
}

// ---------------- bf16 MFMA GEMM: 3-plane pipeline, SINGLE barrier per K-step --------
// C[m,n] = sum_k A[m,k]*W[n,k] + bias[n].  Requires M%128==0, N%128==0, K%32==0, K>=96.
// MODE: 0=plain, 1=relu, 2=+residual R(bf16)
// STATS: 0=none; 1=per-batch sum/sumsq -> stats[b*2(+1)];
//        2=extended LN23 stats (requires N==512): per-batch
//        {Sv, Svv, SGv, SG2v, SG2v2, SGBv} -> stats[b*6..], gamma/beta from gmp/btp.
// Grid is (M/128, N/128) M-fast: blocks sharing an A-panel land on the SAME XCD.
// R8's proven form. R9 4-plane regressed (occupancy 24.5->16.6%): K-loop is
// LDS-BW-bound at this tile -> deeper prefetch cannot help.
template<int MODE, int STATS>
__global__ __launch_bounds__(256) void gemm_mfma(
    const bf16* __restrict__ A, const bf16* __restrict__ W, const float* __restrict__ bias,
    const bf16* __restrict__ R, bf16* __restrict__ C, int M, int N, int K,
    float* __restrict__ stats, const bf16* __restrict__ gmp, const bf16* __restrict__ btp)
{
  __shared__ __align__(16) char smem[49152];
  bf16*  As  = (bf16*)smem;                 // [3][128][32]  24 KB
  bf16*  Bs  = (bf16*)(smem + 24576);       // [3][128][32]  24 KB
  float* Lf  = (float*)smem;                // [32][132] fp32 epilogue staging (16896 B)
  float* red = (float*)(smem + 16896);      // up to 6*256 floats stats reduction

  const int tid  = threadIdx.x;
  const int bm   = blockIdx.x * 128;
  const int bn   = blockIdx.y * 128;
  const int w    = tid >> 6;
  const int lane = tid & 63;
  const int qd   = lane >> 4;
  const int ln   = lane & 15;
  const int wr   = (w >> 1) * 64;
  const int wc   = (w & 1) * 64;

  const int r0 = lane >> 2;
  const int ch = (lane & 3) * 8;
  const bf16* Ag0 = A + (size_t)(bm + w*16 + r0) * K + ch;
  const bf16* Ag1 = Ag0 + (size_t)64 * K;
  const bf16* Bg0 = W + (size_t)(bn + w*16 + r0) * K + ch;
  const bf16* Bg1 = Bg0 + (size_t)64 * K;
  const int lo = w*512 + lane*8;            // offset within a 4096-elem plane

  f32x4 acc[4][4] = {};
  const int nt = K >> 5;

  // prologue: stage tiles 0,1 into planes 0,1
  async16(Ag0, As + lo);
  async16(Ag1, As + lo + 2048);
  async16(Bg0, Bs + lo);
  async16(Bg1, Bs + lo + 2048);
  async16(Ag0 + 32, As + 4096 + lo);
  async16(Ag1 + 32, As + 4096 + lo + 2048);
  async16(Bg0 + 32, Bs + 4096 + lo);
  async16(Bg1 + 32, Bs + 4096 + lo + 2048);

  int pcur = 0;                              // plane holding tile t
  for (int t = 0; t < nt; t++) {
    if (t + 1 < nt) {
      asm volatile("s_waitcnt vmcnt(4)" ::: "memory");   // tile-t landed; t+1 in flight
    } else {
      asm volatile("s_waitcnt vmcnt(0)" ::: "memory");
    }
    __builtin_amdgcn_s_barrier();                        // tile t visible to all waves

    const int cur = pcur << 12;
    short8 af[4], bfr[4];
#pragma unroll
    for (int i = 0; i < 4; i++) af[i]  = *(const short8*)(As + cur + (wr + i*16 + ln)*32 + qd*8);
#pragma unroll
    for (int j = 0; j < 4; j++) bfr[j] = *(const short8*)(Bs + cur + (wc + j*16 + ln)*32 + qd*8);

    if (t + 2 < nt) {
      int pst = pcur - 1; if (pst < 0) pst = 2;   // (pcur+2)%3
      const int nxt = pst << 12;
      const int k0  = (t + 2) << 5;
      async16(Ag0 + k0, As + nxt + lo);
      async16(Ag1 + k0, As + nxt + lo + 2048);
      async16(Bg0 + k0, Bs + nxt + lo);
      async16(Bg1 + k0, Bs + nxt + lo + 2048);
    }

#pragma unroll
    for (int i = 0; i < 4; i++)
#pragma unroll
      for (int j = 0; j < 4; j++)
        acc[i][j] = __builtin_amdgcn_mfma_f32_16x16x32_bf16(af[i], bfr[j], acc[i][j], 0, 0, 0);

    pcur = pcur + 1 == 3 ? 0 : pcur + 1;
  }
  __syncthreads();                           // all reads done before Lf aliases planes

  // ---- epilogue: 4 chunks of 32 rows; stage fp32 in LDS, readback coalesced ----
  float s_acc = 0.f, ss_acc = 0.f;
  float a2 = 0.f, a3 = 0.f, a4 = 0.f, a5 = 0.f;   // STATS==2 weighted sums
  const int lrbase = (w >> 1)*16 + qd*4;
#pragma unroll
  for (int i = 0; i < 4; i++) {
#pragma unroll
    for (int j = 0; j < 4; j++) {
      const int col = wc + j*16 + ln;
#pragma unroll
      for (int rg = 0; rg < 4; rg++)
        Lf[(lrbase + rg)*132 + col] = acc[i][j][rg];
    }
    __syncthreads();
    // readback: 2 pairs of float4 per thread -> one 16B bf16 store each
#pragma unroll
    for (int pz = 0; pz < 2; pz++) {
      const int q   = tid + pz*256;
      const int r   = q >> 4;            // 0..31
      const int nof = (q & 15)*8;        // 0..120
      const int m   = bm + (r >> 4)*64 + i*16 + (r & 15);
      const int n   = bn + nof;
      f32x4 v0 = *(const f32x4*)(Lf + r*132 + nof);
      f32x4 v1 = *(const f32x4*)(Lf + r*132 + nof + 4);
      f32x4 b0 = *(const f32x4*)(bias + n);
      f32x4 b1 = *(const f32x4*)(bias + n + 4);
      float vals[8];
#pragma unroll
      for (int e = 0; e < 4; e++) { vals[e] = v0[e] + b0[e]; vals[4+e] = v1[e] + b1[e]; }
      if (MODE == 1) {
#pragma unroll
        for (int e = 0; e < 8; e++) vals[e] = fmaxf(vals[e], 0.f);
      }
      if (MODE == 2) {
        const uint4 rv = *(const uint4*)((const unsigned short*)R + (size_t)m * N + n);
        const unsigned short* rp = (const unsigned short*)&rv;
#pragma unroll
        for (int e = 0; e < 8; e++) vals[e] += bu2f(rp[e]);
      }
      if (STATS == 1) {
#pragma unroll
        for (int e = 0; e < 8; e++) { s_acc += vals[e]; ss_acc += vals[e]*vals[e]; }
      }
      if (STATS == 2) {
        const int ei = ((m & 511) << 9) + n;     // N==512 layout
        const uint4 gv = *(const uint4*)((const unsigned short*)gmp + ei);
        const uint4 bv = *(const uint4*)((const unsigned short*)btp + ei);
        const unsigned short* gp = (const unsigned short*)&gv;
        const unsigned short* bp = (const unsigned short*)&bv;
#pragma unroll
        for (int e = 0; e < 8; e++) {
          const float vv = vals[e];
          const float G  = bu2f(gp[e]);
          const float Bv = bu2f(bp[e]);
          s_acc += vv; ss_acc += vv*vv;
          a2 += G*vv; a3 += G*G*vv; a4 += G*G*vv*vv; a5 += G*Bv*vv;
        }
      }
      uint4 o; unsigned short* op = (unsigned short*)&o;
#pragma unroll
      for (int e = 0; e < 8; e++) op[e] = f2bu(vals[e]);
      *(uint4*)((unsigned short*)C + (size_t)m * N + n) = o;
    }
    __syncthreads();
  }

  if (STATS == 1) {
    red[tid] = s_acc; red[256 + tid] = ss_acc;
    __syncthreads();
    for (int st = 128; st; st >>= 1) {
      if (tid < st) { red[tid] += red[tid + st]; red[256 + tid] += red[256 + tid + st]; }
      __syncthreads();
    }
    if (tid == 0) {
      const int b = bm >> 9;
      atomicAdd(&stats[b*2],     red[0]);
      atomicAdd(&stats[b*2 + 1], red[256]);
    }
  }
  if (STATS == 2) {
    float v6[6] = { s_acc, ss_acc, a2, a3, a4, a5 };
#pragma unroll
    for (int q2 = 0; q2 < 6; q2++) red[q2*256 + tid] = v6[q2];
    __syncthreads();
    for (int st = 128; st; st >>= 1) {
      if (tid < st)
#pragma unroll
        for (int q2 = 0; q2 < 6; q2++) red[q2*256 + tid] += red[q2*256 + tid + st];
      __syncthreads();
    }
    if (tid == 0) {
      const int b = bm >> 9;
#pragma unroll
      for (int q2 = 0; q2 < 6; q2++) atomicAdd(&stats[b*6 + q2], red[q2*256]);
    }
  }
}

// ---------------- attention: chunked K/V staging overlapped with compute (T14) -------
// qkv: [M][1536] = [b*512+s][q(512)|k(512)|v(512)], head h at columns h*64.
// One block per (b,h); 16 waves; each wave does 32 queries x 512 keys.
// Keys split in 2 chunks of 256; chunk-1 staged during chunk-0 compute with counted
// waits + raw barrier. R10's 4-chunk variant spilled (VGPR 64 + 200MB scratch):
// 2 chunks is the codegen-safe depth.
__global__ __launch_bounds__(1024, 4) void attn_lds(const bf16* __restrict__ qkv,
                                                    bf16* __restrict__ cat)
{
  __shared__ bf16 Ks[2 * 512 * 32];     // 64 KB [ks][key][32]
  __shared__ bf16 Vs[64 * 520];         // 65 KB [dk][key] padded
  __shared__ bf16 pbuf[16][16][40];     // 20 KB per-wave prob staging

  const int tid  = threadIdx.x;
  const int w    = tid >> 6;
  const int lane = tid & 63;
  const int qd   = lane >> 4;
  const int ln   = lane & 15;
  const int bh   = blockIdx.x;
  const int b    = bh >> 3, h = bh & 7;
  const bf16* base = qkv + (size_t)b * 512 * NQKV + h * 64;

  // --- stage K chunk 0 (keys 0..255): [ks][key][32] layout ---
#pragma unroll
  for (int r = 0; r < 2; r++) {
    int c = tid + r*1024;                       // [0,2048)
    int part = c & 3, key = (c >> 2) & 255, ks = c >> 10;
    async16(base + (size_t)key * NQKV + 512 + ks*32 + part*8,
            Ks + ks*16384 + key*32 + part*8);
  }
  // --- stage V chunk 0 transposed: Vs[dk][key], conflict-free lane<->key mapping ---
#pragma unroll
  for (int r = 0; r < 2; r++) {
    int c = tid + r*1024;
    int dkg = c >> 8, key = c & 255;
    uint4 vv = *(const uint4*)(base + (size_t)key * NQKV + 1024 + dkg*8);
    const unsigned short* pv = (const unsigned short*)&vv;
#pragma unroll
    for (int j = 0; j < 8; j++)
      *(unsigned short*)&Vs[(dkg*8 + j)*520 + key] = pv[j];
  }
  // --- Q B-frags for this wave's 32 queries ---
  short8 bq[2][2];
#pragma unroll
  for (int qt = 0; qt < 2; qt++)
#pragma unroll
    for (int ks = 0; ks < 2; ks++)
      bq[qt][ks] = *(const short8*)(base + (size_t)(w*32 + qt*16 + ln) * NQKV + ks*32 + qd*8);

  __syncthreads();                              // chunk 0 visible

  // --- issue chunk 1 staging (keys 256..511): K direct-to-LDS, V into registers ---
#pragma unroll
  for (int r = 0; r < 2; r++) {
    int c = tid + r*1024;
    int part = c & 3, key = 256 + ((c >> 2) & 255), ks = c >> 10;
    async16(base + (size_t)key * NQKV + 512 + ks*32 + part*8,
            Ks + ks*16384 + key*32 + part*8);
  }
  uint4 vhold[2]; int vdst[2];
#pragma unroll
  for (int r = 0; r < 2; r++) {
    int c = tid + r*1024;
    int dkg = c >> 8, key = 256 + (c & 255);
    vhold[r] = *(const uint4*)(base + (size_t)key * NQKV + 1024 + dkg*8);
    vdst[r] = dkg*8*520 + key;
  }
  asm volatile("" ::: "memory");                // pin load issue before compute

  bf16 (*pb)[40] = pbuf[w];
  f32x4 o[2][4] = {};
  float l[2] = {0.f, 0.f};

  for (int half = 0; half < 2; half++) {
    for (int st = half*8; st < half*8 + 8; st++) {
      short8 ak[2][2];
#pragma unroll
      for (int kt = 0; kt < 2; kt++)
#pragma unroll
        for (int ks = 0; ks < 2; ks++)
          ak[kt][ks] = *(const short8*)(Ks + ks*16384 + (st*32 + kt*16 + ln)*32 + qd*8);
      f32x4 s[2][2] = {};
#pragma unroll
      for (int kt = 0; kt < 2; kt++)
#pragma unroll
        for (int qt = 0; qt < 2; qt++) {
          s[kt][qt] = __builtin_amdgcn_mfma_f32_16x16x32_bf16(ak[kt][0], bq[qt][0], s[kt][qt], 0, 0, 0);
          s[kt][qt] = __builtin_amdgcn_mfma_f32_16x16x32_bf16(ak[kt][1], bq[qt][1], s[kt][qt], 0, 0, 0);
        }
      float e[2][2][4];
#pragma unroll
      for (int kt = 0; kt < 2; kt++)
#pragma unroll
        for (int qt = 0; qt < 2; qt++)
#pragma unroll
          for (int rg = 0; rg < 4; rg++) {
            float ev = __expf(s[kt][qt][rg] * 0.125f);
            e[kt][qt][rg] = ev;
            l[qt] += ev;
          }
#pragma unroll
      for (int qt = 0; qt < 2; qt++) {
#pragma unroll
        for (int kt = 0; kt < 2; kt++) {
          uint2 pk;
          pk.x = (unsigned)f2bu(e[kt][qt][0]) | ((unsigned)f2bu(e[kt][qt][1]) << 16);
          pk.y = (unsigned)f2bu(e[kt][qt][2]) | ((unsigned)f2bu(e[kt][qt][3]) << 16);
          *(uint2*)&pb[ln][kt*16 + qd*4] = pk;
        }
        short8 ap = *(const short8*)&pb[ln][qd*8];
#pragma unroll
        for (int nt = 0; nt < 4; nt++) {
          short8 bv = *(const short8*)(Vs + (nt*16 + ln)*520 + st*32 + qd*8);
          o[qt][nt] = __builtin_amdgcn_mfma_f32_16x16x32_bf16(ap, bv, o[qt][nt], 0, 0, 0);
        }
      }
    }
    if (half == 0) {
      // land chunk 1: V regs -> LDS (K async16 already targeted LDS directly)
      asm volatile("s_waitcnt vmcnt(0)" ::: "memory");
#pragma unroll
      for (int r = 0; r < 2; r++) {
        const unsigned short* pv = (const unsigned short*)&vhold[r];
#pragma unroll
        for (int j = 0; j < 8; j++)
          *(unsigned short*)&Vs[vdst[r] + j*520] = pv[j];
      }
      asm volatile("s_waitcnt lgkmcnt(0)" ::: "memory");
      __builtin_amdgcn_s_barrier();             // chunk 1 visible to all waves
    }
  }

#pragma unroll
  for (int qt = 0; qt < 2; qt++) {
    l[qt] += __shfl_xor(l[qt], 16);
    l[qt] += __shfl_xor(l[qt], 32);
  }
  float inv0 = 1.f / l[0], inv1 = 1.f / l[1];

  const size_t crow0 = (size_t)(b*S_ + w*32) * D_ + h*DK_;
#pragma unroll
  for (int qt = 0; qt < 2; qt++) {
#pragma unroll
    for (int rg = 0; rg < 4; rg++) {
      float ivv = __shfl(qt ? inv1 : inv0, qd*4 + rg);
      int r = qt*16 + qd*4 + rg;
      bf16* cp = cat + crow0 + (size_t)r * D_ + ln;
#pragma unroll
      for (int nt = 0; nt < 4; nt++) cp[nt*16] = f2b(o[qt][nt][rg] * ivv);
    }
  }
}

// ---------------- LN1 apply (bf16 in/out), stats precomputed, bf16 gamma/beta --------
__global__ __launch_bounds__(256) void ln_b16_b16(const bf16* __restrict__ in,
    const float* __restrict__ stats, const bf16* __restrict__ gamma,
    const bf16* __restrict__ beta, bf16* __restrict__ out)
{
  const int b = blockIdx.x >> 4;
  const float invN = 1.f / (float)(S_*D_);
  const float m    = stats[b*2] * invN;
  const float var  = stats[b*2+1] * invN - m*m;
  const float rstd = rsqrtf(var + 1e-5f);
  size_t v = (size_t)b * 65536 + (blockIdx.x & 15) * 4096 + threadIdx.x;
#pragma unroll 4
  for (int it = 0; it < 16; it++, v += 256) {
    us4 xi = *(const us4*)((const unsigned short*)in + v*4);
    size_t e = (v * 4) & (S_*D_ - 1);
    us4 g4 = *(const us4*)((const unsigned short*)gamma + e);
    us4 b4 = *(const us4*)((const unsigned short*)beta + e);
    us4 o;
    o[0] = f2bu((bu2f(xi[0]) - m) * rstd * bu2f(g4[0]) + bu2f(b4[0]));
    o[1] = f2bu((bu2f(xi[1]) - m) * rstd * bu2f(g4[1]) + bu2f(b4[1]));
    o[2] = f2bu((bu2f(xi[2]) - m) * rstd * bu2f(g4[2]) + bu2f(b4[2]));
    o[3] = f2bu((bu2f(xi[3]) - m) * rstd * bu2f(g4[3]) + bu2f(b4[3]));
    *(us4*)((unsigned short*)out + v*4) = o;
  }
}

// ---------------- fused LN2+LN3: single pass yB -> out -------------------------------
// LN2 params (m2,r2) from extended stats {Sv,Svv}; LN3 params derived ALGEBRAICALLY:
//   Sy  = r2*(SGv - m2*CG) + CB
//   SSy = r2^2*(SG2v2 - 2*m2*SG2v + m2^2*CG2) + 2*r2*(SGBv - m2*CGB) + CB2
// where y2 = (v-m2)*r2*g + b; out = (y2-m3)*r3*g + b. Eliminates the y2 pass.
__global__ __launch_bounds__(256) void ln23_fused(const bf16* __restrict__ in,
    const float* __restrict__ st2x, const float* __restrict__ cst,
    const bf16* __restrict__ gamma, const bf16* __restrict__ beta,
    void* __restrict__ out, const int* __restrict__ flag)
{
  const bool f32 = (*flag != 0);
  const int b = blockIdx.x >> 4;
  const float invN = 1.f / (float)(S_*D_);
  const float Sv   = st2x[b*6+0], Svv  = st2x[b*6+1];
  const float SGv  = st2x[b*6+2], SG2v = st2x[b*6+3];
  const float SG2v2= st2x[b*6+4], SGBv = st2x[b*6+5];
  const float CG = cst[0], CG2 = cst[1], CGB = cst[2], CB = cst[3], CB2 = cst[4];
  const float m2 = Sv * invN;
  const float r2 = rsqrtf(Svv * invN - m2*m2 + 1e-5f);
  const float Sy  = r2 * (SGv - m2*CG) + CB;
  const float SSy = r2*r2 * (SG2v2 - 2.f*m2*SG2v + m2*m2*CG2)
                  + 2.f*r2 * (SGBv - m2*CGB) + CB2;
  const float m3 = Sy * invN;
  const float r3 = rsqrtf(SSy * invN - m3*m3 + 1e-5f);

  size_t v = (size_t)b * 65536 + (blockIdx.x & 15) * 4096 + threadIdx.x;
#pragma unroll 4
  for (int it = 0; it < 16; it++, v += 256) {
    us4 xi = *(const us4*)((const unsigned short*)in + v*4);
    size_t e = (v * 4) & (S_*D_ - 1);
    us4 g4 = *(const us4*)((const unsigned short*)gamma + e);
    us4 b4 = *(const us4*)((const unsigned short*)beta + e);
    float4 o;
    {
      float G = bu2f(g4[0]), B = bu2f(b4[0]);
      float y2 = (bu2f(xi[0]) - m2) * r2 * G + B;
      o.x = (y2 - m3) * r3 * G + B;
    }
    {
      float G = bu2f(g4[1]), B = bu2f(b4[1]);
      float y2 = (bu2f(xi[1]) - m2) * r2 * G + B;
      o.y = (y2 - m3) * r3 * G + B;
    }
    {
      float G = bu2f(g4[2]), B = bu2f(b4[2]);
      float y2 = (bu2f(xi[2]) - m2) * r2 * G + B;
      o.z = (y2 - m3) * r3 * G + B;
    }
    {
      float G = bu2f(g4[3]), B = bu2f(b4[3]);
      float y2 = (bu2f(xi[3]) - m2) * r2 * G + B;
      o.w = (y2 - m3) * r3 * G + B;
    }
    if (f32) ((float4*)out)[v] = o;
    else {
      us4 ob;
      ob[0] = f2bu(o.x); ob[1] = f2bu(o.y); ob[2] = f2bu(o.z); ob[3] = f2bu(o.w);
      *(us4*)((unsigned short*)out + v*4) = ob;
    }
  }
}

// ---------------- launch ----------------
extern "C" void kernel_launch(void* const* d_in, const int* in_sizes, int n_in,
                              void* d_out, int out_size, void* d_ws, size_t ws_size,
                              hipStream_t stream)
{
  char* p = (char*)d_ws;
  auto alloc_b = [&](size_t elems) { void* r = p; p += elems * 2; return (bf16*)r; };
  auto alloc_f = [&](size_t elems) {
    p = (char*)(((uintptr_t)p + 15) & ~(uintptr_t)15); void* r = p; p += elems * 4; return (float*)r;
  };

  bf16* xb   = alloc_b(MSD);            // x bf16
  bf16* qkv  = alloc_b(3 * MSD);        // [M][1536] natural
  bf16* catb = alloc_b(MSD);
  bf16* wqkv = alloc_b(3 * 512 * 512);
  bf16* wo   = alloc_b(512 * 512);
  bf16* w1p  = alloc_b((size_t)FFP * 512);
  bf16* w2p  = alloc_b((size_t)FFP * FFP);
  bf16* w3p  = alloc_b((size_t)512 * FFP);
  bf16* gm   = alloc_b((size_t)S_ * D_);   // gamma bf16
  bf16* bt   = alloc_b((size_t)S_ * D_);   // beta  bf16
  float* bqkv= alloc_f(3 * 512);
  float* bo  = alloc_f(512);
  float* b1p = alloc_f(FFP);
  float* b2p = alloc_f(FFP);
  float* b3  = alloc_f(512);
  float* stats = alloc_f(320);          // st1(64) | cst(16) | st2x(192) | pad
  int*   flag  = (int*)alloc_f(16);
  if ((size_t)(p - (char*)d_ws) > ws_size) return;

  // intermediates aliased into dead regions:
  bf16* y1b = qkv;                      // LN1 out [M][512]   (qkv dead after attn)
  bf16* f1  = qkv + MSD;                // [M][FFP]
  bf16* f2  = qkv + MSD + (size_t)M_ * FFP;
  bf16* yA  = qkv + 2 * MSD;            // out-proj + residual (bf16)
  bf16* yB  = catb;                     // FFN3 + residual     (catb dead after out-proj)
  float* st1  = stats;                  // LN1 stats, 2/batch
  float* cst  = stats + 64;             // gamma/beta consts: CG,CG2,CGB,CB,CB2
  float* st2x = stats + 80;             // extended LN23 stats, 6/batch

  detect_kernel<<<1, 256, 0, stream>>>((const unsigned short*)d_in[0], flag, stats);

  Segs sg;
  // {src, dst, srcRows, srcK, dstK, total}
  sg.s[0]  = { d_in[1],  wqkv,               512, 512, 512, 512*512 };
  sg.s[1]  = { d_in[3],  wqkv + 512*512,     512, 512, 512, 512*512 };
  sg.s[2]  = { d_in[5],  wqkv + 2*512*512,   512, 512, 512, 512*512 };
  sg.s[3]  = { d_in[7],  wo,                 512, 512, 512, 512*512 };
  sg.s[4]  = { d_in[9],  w1p,                FF_, 512, 512, FFP*512 };
  sg.s[5]  = { d_in[11], w2p,                FF_, FF_, FFP, FFP*FFP };
  sg.s[6]  = { d_in[13], w3p,                512, FF_, FFP, 512*FFP };
  sg.s[7]  = { d_in[2],  bqkv,               1, 512, 512, 512 };
  sg.s[8]  = { d_in[4],  bqkv + 512,         1, 512, 512, 512 };
  sg.s[9]  = { d_in[6],  bqkv + 1024,        1, 512, 512, 512 };
  sg.s[10] = { d_in[8],  bo,                 1, 512, 512, 512 };
  sg.s[11] = { d_in[10], b1p,                1, FF_, FFP, FFP };
  sg.s[12] = { d_in[12], b2p,                1, FF_, FFP, FFP };
  sg.s[13] = { d_in[14], b3,                 1, 512, 512, 512 };
  sg.s[14] = { d_in[15], gm,                 1, S_*D_, S_*D_, S_*D_ };
  sg.s[15] = { d_in[16], bt,                 1, S_*D_, S_*D_, S_*D_ };
  sg.isbf = 0xC07F;                     // weights + gamma/beta are bf16

  // fused front-end: x convert + seg convert + gamma/beta constants (one launch)
  cvt_fused<<<3136, 256, 0, stream>>>(d_in[0], xb, sg, flag, d_in[15], d_in[16], cst);

  dim3 blk(256);

  // fused QKV projection: plain GEMM, natural output [M][1536]
  gemm_mfma<0, 0><<<dim3(M_/128, NQKV/128), blk, 0, stream>>>(
      xb, wqkv, bqkv, nullptr, qkv, M_, NQKV, 512, nullptr, nullptr, nullptr);

  attn_lds<<<B_*H_, 1024, 0, stream>>>(qkv, catb);

  // output projection + residual x -> bf16 yA, fused LN1 stats
  gemm_mfma<2, 1><<<dim3(M_/128, 4), blk, 0, stream>>>(
      catb, wo, bo, xb, yA, M_, 512, 512, st1, nullptr, nullptr);

  ln_b16_b16<<<512, blk, 0, stream>>>(yA, st1, gm, bt, y1b);

  // FFN (padded to 256)
  gemm_mfma<1, 0><<<dim3(M_/128, 2), blk, 0, stream>>>(
      y1b, w1p, b1p, nullptr, f1, M_, FFP, 512, nullptr, nullptr, nullptr);
  gemm_mfma<1, 0><<<dim3(M_/128, 2), blk, 0, stream>>>(
      f1, w2p, b2p, nullptr, f2, M_, FFP, FFP, nullptr, nullptr, nullptr);
  // FFN3 + residual -> yB, with EXTENDED stats for the LN2+LN3 fusion
  gemm_mfma<2, 2><<<dim3(M_/128, 4), blk, 0, stream>>>(
      f2, w3p, b3, y1b, yB, M_, 512, FFP, st2x, gm, bt);

  // fused LN2-apply + LN3 (stats derived algebraically) -> out, single pass
  ln23_fused<<<512, blk, 0, stream>>>(yB, st2x, cst, gm, bt, d_out, flag);
}

// Round 14
// 260.696 us; speedup vs baseline: 1.5764x; 1.0104x over previous
//
#include <hip/hip_runtime.h>
#include <hip/hip_bf16.h>
#include <stdint.h>

// encoder_layer: B=32,S=512,D=512,H=8,DK=64,FF=200. bf16 MFMA, fp32 LN stats.
#define B_  32
#define S_  512
#define D_  512
#define H_  8
#define DK_ 64
#define FF_ 200
#define FFP 256                 // FF padded to 256 (zero-fill) -> unguarded GEMMs
#define M_  (B_*S_)             // 16384
#define MSD ((size_t)B_*S_*D_)  // 8388608
#define NQKV 1536

typedef __hip_bfloat16 bf16;
typedef __attribute__((ext_vector_type(8))) short short8;
typedef __attribute__((ext_vector_type(4))) float f32x4;
typedef __attribute__((ext_vector_type(4))) unsigned short us4;

__device__ inline float b2f(bf16 v) { return __bfloat162float(v); }
__device__ inline bf16  f2b(float v){ return __float2bfloat16(v); }
__device__ inline unsigned short f2bu(float v) {
  union { bf16 h; unsigned short u; } cv; cv.h = __float2bfloat16(v); return cv.u;
}
__device__ inline float bu2f(unsigned short u) {
  union { unsigned short u; bf16 h; } cv; cv.u = u; return b2f(cv.h);
}
__device__ __forceinline__ void async16(const bf16* g, bf16* l) {
  __builtin_amdgcn_global_load_lds((const __attribute__((address_space(1))) void*)g,
                                   (__attribute__((address_space(3))) void*)l, 16, 0, 0);
}

// ---------------- dtype detection (flag=1 -> fp32 inputs) + stats zero ----------------
__global__ void detect_kernel(const unsigned short* __restrict__ xu, int* __restrict__ flag,
                              float* __restrict__ stats) {
  __shared__ int mx[256];
  const int tid = threadIdx.x;
  if (tid < 160) { stats[tid] = 0.f; stats[tid + 160] = 0.f; }   // zero 320 floats
  int m = 0;
  for (int i = tid * 2; i < 8192; i += 512) {
    int e = (xu[i] >> 7) & 0xFF;
    m = m > e ? m : e;
  }
  mx[tid] = m;
  __syncthreads();
  for (int st = 128; st; st >>= 1) {
    if (tid < st) mx[tid] = mx[tid] > mx[tid + st] ? mx[tid] : mx[tid + st];
    __syncthreads();
  }
  if (tid == 0) *flag = (mx[0] >= 0xC0) ? 1 : 0;
}

// ---------------- merged weight/bias/gamma convert with zero-padding ----------------
struct Seg { const void* src; void* dst; int srcRows, srcK, dstK, total; };
struct Segs { Seg s[16]; unsigned int isbf; };

// ---------------- fused front-end: x-convert + seg-convert + gamma/beta constants ----
// One launch, 3 block roles (all independent given flag from detect_kernel):
//   bid <  2048: x convert, 8 elems/thread (bf16 copy or f32->bf16)
//   bid <  3072: weight/bias/gamma convert with zero-padding (seg = (bid-2048)&15)
//   bid >= 3072: gamma/beta constants CG,CG2,CGB,CB,CB2 from RAW inputs with the
//                identical f2bu rounding -> bit-identical to reading converted gm/bt.
__global__ __launch_bounds__(256) void cvt_fused(const void* __restrict__ xin,
    bf16* __restrict__ xout, Segs sg, const int* __restrict__ flag,
    const void* __restrict__ gsrc, const void* __restrict__ bsrc,
    float* __restrict__ cst)
{
  const bool f32in = (*flag != 0);
  const int bid = blockIdx.x;
  const int tid = threadIdx.x;

  if (bid < 2048) {
    // ---- x convert ----
    size_t i = ((size_t)bid * 256 + tid) * 8;
    const size_t stride = (size_t)2048 * 256 * 8;
    for (; i < MSD; i += stride) {
      if (f32in) {
        const float4 a = ((const float4*)xin)[i/4];
        const float4 b = ((const float4*)xin)[i/4 + 1];
        uint4 o; unsigned short* po = (unsigned short*)&o;
        po[0]=f2bu(a.x); po[1]=f2bu(a.y); po[2]=f2bu(a.z); po[3]=f2bu(a.w);
        po[4]=f2bu(b.x); po[5]=f2bu(b.y); po[6]=f2bu(b.z); po[7]=f2bu(b.w);
        *(uint4*)((unsigned short*)xout + i) = o;
      } else {
        *(uint4*)((unsigned short*)xout + i) = *(const uint4*)((const unsigned short*)xin + i);
      }
    }
  } else if (bid < 3072) {
    // ---- seg convert ----
    const int b2  = bid - 2048;
    const int seg = b2 & 15;
    const Seg sd = sg.s[seg];
    const int stride = 64 * 256;                 // 1024/16 blocks per seg
    const bool nopad = (sd.srcK == sd.dstK);
    for (int i = (b2 >> 4) * 256 + tid; i < sd.total; i += stride) {
      int sidx; bool valid;
      if (nopad) { sidx = i; valid = (i < sd.srcRows * sd.srcK); }
      else {
        int r = i / sd.dstK, c = i - r * sd.dstK;
        valid = (r < sd.srcRows) && (c < sd.srcK);
        sidx = r * sd.srcK + c;
      }
      float v = 0.f;
      if (valid) v = f32in ? ((const float*)sd.src)[sidx] : b2f(((const bf16*)sd.src)[sidx]);
      if (sg.isbf & (1u << seg)) ((unsigned short*)sd.dst)[i] = f2bu(v);
      else                       ((float*)sd.dst)[i] = v;
    }
  } else {
    // ---- gamma/beta constants (bf16-rounded, from raw inputs) ----
    __shared__ float red[5][256];
    const int b3 = bid - 3072;                   // [0,64)
    float c0=0.f, c1=0.f, c2=0.f, c3=0.f, c4=0.f;
#pragma unroll
    for (int k = 0; k < 4; k++) {
      const int grp = b3*256 + tid + k*16384;    // us4/float4 group id, 65536 total
      float G[4], Bv[4];
      if (f32in) {
        float4 ga = ((const float4*)gsrc)[grp];
        float4 ba = ((const float4*)bsrc)[grp];
        G[0]=bu2f(f2bu(ga.x)); G[1]=bu2f(f2bu(ga.y)); G[2]=bu2f(f2bu(ga.z)); G[3]=bu2f(f2bu(ga.w));
        Bv[0]=bu2f(f2bu(ba.x)); Bv[1]=bu2f(f2bu(ba.y)); Bv[2]=bu2f(f2bu(ba.z)); Bv[3]=bu2f(f2bu(ba.w));
      } else {
        us4 g4 = *(const us4*)((const unsigned short*)gsrc + grp*4);
        us4 b4 = *(const us4*)((const unsigned short*)bsrc + grp*4);
#pragma unroll
        for (int j = 0; j < 4; j++) { G[j] = bu2f(g4[j]); Bv[j] = bu2f(b4[j]); }
      }
#pragma unroll
      for (int j = 0; j < 4; j++) {
        c0 += G[j]; c1 += G[j]*G[j]; c2 += G[j]*Bv[j]; c3 += Bv[j]; c4 += Bv[j]*Bv[j];
      }
    }
    red[0][tid]=c0; red[1][tid]=c1; red[2][tid]=c2; red[3][tid]=c3; red[4][tid]=c4;
    __syncthreads();
    for (int st = 128; st; st >>= 1) {
      if (tid < st)
#pragma unroll
        for (int q = 0; q < 5; q++) red[q][tid] += red[q][tid + st];
      __syncthreads();
    }
    if (tid == 0)
#pragma unroll
      for (int q = 0; q < 5; q++) atomicAdd(&cst[q], red[q][0]);
  }
}

// ---------------- bf16 MFMA GEMM: 3-plane pipeline, SINGLE barrier per K-step --------
// C[m,n] = sum_k A[m,k]*W[n,k] + bias[n].  M%BM==0, N%128==0, K%32==0, K>=96.
// BM: 128 (wave tile 64x64, acc[4][4]) or 64 (wave tile 32x64, acc[2][4]).
//   BM=64 doubles the grid for narrow-N GEMMs (FFN1/2 were 256 blocks = 1 block/CU
//   = 1 wave/SIMD, fully latency-exposed; BM=64 -> 512 blocks = 2/CU = 8 waves/CU).
// MODE: 0=plain, 1=relu, 2=+residual R(bf16)
// STATS: 0=none; 1=per-batch sum/sumsq; 2=extended LN23 stats (N==512).
// Grid is (M/BM, N/128) M-fast: blocks sharing an A-panel land on the SAME XCD.
template<int MODE, int STATS, int BM>
__global__ __launch_bounds__(256) void gemm_mfma(
    const bf16* __restrict__ A, const bf16* __restrict__ W, const float* __restrict__ bias,
    const bf16* __restrict__ R, bf16* __restrict__ C, int M, int N, int K,
    float* __restrict__ stats, const bf16* __restrict__ gmp, const bf16* __restrict__ btp)
{
  constexpr int APL = BM * 32;              // A plane elems (4096 or 2048)
  constexpr int ACH = BM / 64;              // A chunks per thread (2 or 1)
  constexpr int LP  = ACH + 2;              // loads per tile per thread (4 or 3)
  constexpr int NFR = BM / 32;              // A frags per wave (4 or 2)
  __shared__ __align__(16) char smem[3*APL*2 + 24576];
  bf16*  As  = (bf16*)smem;                 // [3][BM][32]
  bf16*  Bs  = (bf16*)(smem + 3*APL*2);     // [3][128][32]
  float* Lf  = (float*)smem;                // [32][132] fp32 epilogue staging (16896 B)
  float* red = (float*)(smem + 16896);      // up to 6*256 floats stats reduction

  const int tid  = threadIdx.x;
  const int bm   = blockIdx.x * BM;
  const int bn   = blockIdx.y * 128;
  const int w    = tid >> 6;
  const int lane = tid & 63;
  const int qd   = lane >> 4;
  const int ln   = lane & 15;
  const int wr   = (w >> 1) * (BM/2);
  const int wc   = (w & 1) * 64;

  const int r0 = lane >> 2;
  const int ch = (lane & 3) * 8;
  const bf16* Ag0 = A + (size_t)(bm + w*16 + r0) * K + ch;
  const bf16* Ag1 = Ag0 + (size_t)64 * K;   // used only when BM==128
  const bf16* Bg0 = W + (size_t)(bn + w*16 + r0) * K + ch;
  const bf16* Bg1 = Bg0 + (size_t)64 * K;
  const int lo = w*512 + lane*8;            // offset within a plane (tid*8)

  f32x4 acc[NFR][4] = {};
  const int nt = K >> 5;

  // prologue: stage tiles 0,1 into planes 0,1
#pragma unroll
  for (int pt = 0; pt < 2; pt++) {
    const int ko = pt*32;
    async16(Ag0 + ko, As + pt*APL + lo);
    if (ACH == 2) async16(Ag1 + ko, As + pt*APL + lo + 2048);
    async16(Bg0 + ko, Bs + pt*4096 + lo);
    async16(Bg1 + ko, Bs + pt*4096 + lo + 2048);
  }

  int pcur = 0;                              // plane holding tile t
  for (int t = 0; t < nt; t++) {
    if (t + 1 < nt) {
      if (LP == 4) asm volatile("s_waitcnt vmcnt(4)" ::: "memory");
      else         asm volatile("s_waitcnt vmcnt(3)" ::: "memory");
    } else {
      asm volatile("s_waitcnt vmcnt(0)" ::: "memory");
    }
    __builtin_amdgcn_s_barrier();                        // tile t visible to all waves

    const int curA = pcur * APL;
    const int curB = pcur << 12;
    short8 af[NFR], bfr[4];
#pragma unroll
    for (int i = 0; i < NFR; i++) af[i] = *(const short8*)(As + curA + (wr + i*16 + ln)*32 + qd*8);
#pragma unroll
    for (int j = 0; j < 4; j++) bfr[j] = *(const short8*)(Bs + curB + (wc + j*16 + ln)*32 + qd*8);

    if (t + 2 < nt) {
      int pst = pcur - 1; if (pst < 0) pst = 2;   // (pcur+2)%3
      const int k0 = (t + 2) << 5;
      async16(Ag0 + k0, As + pst*APL + lo);
      if (ACH == 2) async16(Ag1 + k0, As + pst*APL + lo + 2048);
      async16(Bg0 + k0, Bs + (pst<<12) + lo);
      async16(Bg1 + k0, Bs + (pst<<12) + lo + 2048);
    }

#pragma unroll
    for (int i = 0; i < NFR; i++)
#pragma unroll
      for (int j = 0; j < 4; j++)
        acc[i][j] = __builtin_amdgcn_mfma_f32_16x16x32_bf16(af[i], bfr[j], acc[i][j], 0, 0, 0);

    pcur = pcur + 1 == 3 ? 0 : pcur + 1;
  }
  __syncthreads();                           // all reads done before Lf aliases planes

  // ---- epilogue: NFR chunks of 32 rows; stage fp32 in LDS, readback coalesced ----
  float s_acc = 0.f, ss_acc = 0.f;
  float a2 = 0.f, a3 = 0.f, a4 = 0.f, a5 = 0.f;   // STATS==2 weighted sums
  const int lrbase = (w >> 1)*16 + qd*4;
#pragma unroll
  for (int i = 0; i < NFR; i++) {
#pragma unroll
    for (int j = 0; j < 4; j++) {
      const int col = wc + j*16 + ln;
#pragma unroll
      for (int rg = 0; rg < 4; rg++)
        Lf[(lrbase + rg)*132 + col] = acc[i][j][rg];
    }
    __syncthreads();
    // readback: 2 pairs of float4 per thread -> one 16B bf16 store each
#pragma unroll
    for (int pz = 0; pz < 2; pz++) {
      const int q   = tid + pz*256;
      const int r   = q >> 4;            // 0..31
      const int nof = (q & 15)*8;        // 0..120
      const int m   = bm + (r >> 4)*(BM/2) + i*16 + (r & 15);
      const int n   = bn + nof;
      f32x4 v0 = *(const f32x4*)(Lf + r*132 + nof);
      f32x4 v1 = *(const f32x4*)(Lf + r*132 + nof + 4);
      f32x4 b0 = *(const f32x4*)(bias + n);
      f32x4 b1 = *(const f32x4*)(bias + n + 4);
      float vals[8];
#pragma unroll
      for (int e = 0; e < 4; e++) { vals[e] = v0[e] + b0[e]; vals[4+e] = v1[e] + b1[e]; }
      if (MODE == 1) {
#pragma unroll
        for (int e = 0; e < 8; e++) vals[e] = fmaxf(vals[e], 0.f);
      }
      if (MODE == 2) {
        const uint4 rv = *(const uint4*)((const unsigned short*)R + (size_t)m * N + n);
        const unsigned short* rp = (const unsigned short*)&rv;
#pragma unroll
        for (int e = 0; e < 8; e++) vals[e] += bu2f(rp[e]);
      }
      if (STATS == 1) {
#pragma unroll
        for (int e = 0; e < 8; e++) { s_acc += vals[e]; ss_acc += vals[e]*vals[e]; }
      }
      if (STATS == 2) {
        const int ei = ((m & 511) << 9) + n;     // N==512 layout
        const uint4 gv = *(const uint4*)((const unsigned short*)gmp + ei);
        const uint4 bv = *(const uint4*)((const unsigned short*)btp + ei);
        const unsigned short* gp = (const unsigned short*)&gv;
        const unsigned short* bp = (const unsigned short*)&bv;
#pragma unroll
        for (int e = 0; e < 8; e++) {
          const float vv = vals[e];
          const float G  = bu2f(gp[e]);
          const float Bv = bu2f(bp[e]);
          s_acc += vv; ss_acc += vv*vv;
          a2 += G*vv; a3 += G*G*vv; a4 += G*G*vv*vv; a5 += G*Bv*vv;
        }
      }
      uint4 o; unsigned short* op = (unsigned short*)&o;
#pragma unroll
      for (int e = 0; e < 8; e++) op[e] = f2bu(vals[e]);
      *(uint4*)((unsigned short*)C + (size_t)m * N + n) = o;
    }
    __syncthreads();
  }

  if (STATS == 1) {
    red[tid] = s_acc; red[256 + tid] = ss_acc;
    __syncthreads();
    for (int st = 128; st; st >>= 1) {
      if (tid < st) { red[tid] += red[tid + st]; red[256 + tid] += red[256 + tid + st]; }
      __syncthreads();
    }
    if (tid == 0) {
      const int b = bm >> 9;
      atomicAdd(&stats[b*2],     red[0]);
      atomicAdd(&stats[b*2 + 1], red[256]);
    }
  }
  if (STATS == 2) {
    float v6[6] = { s_acc, ss_acc, a2, a3, a4, a5 };
#pragma unroll
    for (int q2 = 0; q2 < 6; q2++) red[q2*256 + tid] = v6[q2];
    __syncthreads();
    for (int st = 128; st; st >>= 1) {
      if (tid < st)
#pragma unroll
        for (int q2 = 0; q2 < 6; q2++) red[q2*256 + tid] += red[q2*256 + tid + st];
      __syncthreads();
    }
    if (tid == 0) {
      const int b = bm >> 9;
#pragma unroll
      for (int q2 = 0; q2 < 6; q2++) atomicAdd(&stats[b*6 + q2], red[q2*256]);
    }
  }
}

// ---------------- attention: chunked K/V staging overlapped with compute (T14) -------
// qkv: [M][1536] = [b*512+s][q(512)|k(512)|v(512)], head h at columns h*64.
// One block per (b,h); 16 waves; each wave does 32 queries x 512 keys.
// Keys split in 2 chunks of 256; chunk-1 staged during chunk-0 compute with counted
// waits + raw barrier. R10's 4-chunk variant spilled (VGPR 64 + 200MB scratch):
// 2 chunks is the codegen-safe depth.
__global__ __launch_bounds__(1024, 4) void attn_lds(const bf16* __restrict__ qkv,
                                                    bf16* __restrict__ cat)
{
  __shared__ bf16 Ks[2 * 512 * 32];     // 64 KB [ks][key][32]
  __shared__ bf16 Vs[64 * 520];         // 65 KB [dk][key] padded
  __shared__ bf16 pbuf[16][16][40];     // 20 KB per-wave prob staging

  const int tid  = threadIdx.x;
  const int w    = tid >> 6;
  const int lane = tid & 63;
  const int qd   = lane >> 4;
  const int ln   = lane & 15;
  const int bh   = blockIdx.x;
  const int b    = bh >> 3, h = bh & 7;
  const bf16* base = qkv + (size_t)b * 512 * NQKV + h * 64;

  // --- stage K chunk 0 (keys 0..255): [ks][key][32] layout ---
#pragma unroll
  for (int r = 0; r < 2; r++) {
    int c = tid + r*1024;                       // [0,2048)
    int part = c & 3, key = (c >> 2) & 255, ks = c >> 10;
    async16(base + (size_t)key * NQKV + 512 + ks*32 + part*8,
            Ks + ks*16384 + key*32 + part*8);
  }
  // --- stage V chunk 0 transposed: Vs[dk][key], conflict-free lane<->key mapping ---
#pragma unroll
  for (int r = 0; r < 2; r++) {
    int c = tid + r*1024;
    int dkg = c >> 8, key = c & 255;
    uint4 vv = *(const uint4*)(base + (size_t)key * NQKV + 1024 + dkg*8);
    const unsigned short* pv = (const unsigned short*)&vv;
#pragma unroll
    for (int j = 0; j < 8; j++)
      *(unsigned short*)&Vs[(dkg*8 + j)*520 + key] = pv[j];
  }
  // --- Q B-frags for this wave's 32 queries ---
  short8 bq[2][2];
#pragma unroll
  for (int qt = 0; qt < 2; qt++)
#pragma unroll
    for (int ks = 0; ks < 2; ks++)
      bq[qt][ks] = *(const short8*)(base + (size_t)(w*32 + qt*16 + ln) * NQKV + ks*32 + qd*8);

  __syncthreads();                              // chunk 0 visible

  // --- issue chunk 1 staging (keys 256..511): K direct-to-LDS, V into registers ---
#pragma unroll
  for (int r = 0; r < 2; r++) {
    int c = tid + r*1024;
    int part = c & 3, key = 256 + ((c >> 2) & 255), ks = c >> 10;
    async16(base + (size_t)key * NQKV + 512 + ks*32 + part*8,
            Ks + ks*16384 + key*32 + part*8);
  }
  uint4 vhold[2]; int vdst[2];
#pragma unroll
  for (int r = 0; r < 2; r++) {
    int c = tid + r*1024;
    int dkg = c >> 8, key = 256 + (c & 255);
    vhold[r] = *(const uint4*)(base + (size_t)key * NQKV + 1024 + dkg*8);
    vdst[r] = dkg*8*520 + key;
  }
  asm volatile("" ::: "memory");                // pin load issue before compute

  bf16 (*pb)[40] = pbuf[w];
  f32x4 o[2][4] = {};
  float l[2] = {0.f, 0.f};

  for (int half = 0; half < 2; half++) {
    for (int st = half*8; st < half*8 + 8; st++) {
      short8 ak[2][2];
#pragma unroll
      for (int kt = 0; kt < 2; kt++)
#pragma unroll
        for (int ks = 0; ks < 2; ks++)
          ak[kt][ks] = *(const short8*)(Ks + ks*16384 + (st*32 + kt*16 + ln)*32 + qd*8);
      f32x4 s[2][2] = {};
#pragma unroll
      for (int kt = 0; kt < 2; kt++)
#pragma unroll
        for (int qt = 0; qt < 2; qt++) {
          s[kt][qt] = __builtin_amdgcn_mfma_f32_16x16x32_bf16(ak[kt][0], bq[qt][0], s[kt][qt], 0, 0, 0);
          s[kt][qt] = __builtin_amdgcn_mfma_f32_16x16x32_bf16(ak[kt][1], bq[qt][1], s[kt][qt], 0, 0, 0);
        }
      float e[2][2][4];
#pragma unroll
      for (int kt = 0; kt < 2; kt++)
#pragma unroll
        for (int qt = 0; qt < 2; qt++)
#pragma unroll
          for (int rg = 0; rg < 4; rg++) {
            float ev = __expf(s[kt][qt][rg] * 0.125f);
            e[kt][qt][rg] = ev;
            l[qt] += ev;
          }
#pragma unroll
      for (int qt = 0; qt < 2; qt++) {
#pragma unroll
        for (int kt = 0; kt < 2; kt++) {
          uint2 pk;
          pk.x = (unsigned)f2bu(e[kt][qt][0]) | ((unsigned)f2bu(e[kt][qt][1]) << 16);
          pk.y = (unsigned)f2bu(e[kt][qt][2]) | ((unsigned)f2bu(e[kt][qt][3]) << 16);
          *(uint2*)&pb[ln][kt*16 + qd*4] = pk;
        }
        short8 ap = *(const short8*)&pb[ln][qd*8];
#pragma unroll
        for (int nt = 0; nt < 4; nt++) {
          short8 bv = *(const short8*)(Vs + (nt*16 + ln)*520 + st*32 + qd*8);
          o[qt][nt] = __builtin_amdgcn_mfma_f32_16x16x32_bf16(ap, bv, o[qt][nt], 0, 0, 0);
        }
      }
    }
    if (half == 0) {
      // land chunk 1: V regs -> LDS (K async16 already targeted LDS directly)
      asm volatile("s_waitcnt vmcnt(0)" ::: "memory");
#pragma unroll
      for (int r = 0; r < 2; r++) {
        const unsigned short* pv = (const unsigned short*)&vhold[r];
#pragma unroll
        for (int j = 0; j < 8; j++)
          *(unsigned short*)&Vs[vdst[r] + j*520] = pv[j];
      }
      asm volatile("s_waitcnt lgkmcnt(0)" ::: "memory");
      __builtin_amdgcn_s_barrier();             // chunk 1 visible to all waves
    }
  }

#pragma unroll
  for (int qt = 0; qt < 2; qt++) {
    l[qt] += __shfl_xor(l[qt], 16);
    l[qt] += __shfl_xor(l[qt], 32);
  }
  float inv0 = 1.f / l[0], inv1 = 1.f / l[1];

  const size_t crow0 = (size_t)(b*S_ + w*32) * D_ + h*DK_;
#pragma unroll
  for (int qt = 0; qt < 2; qt++) {
#pragma unroll
    for (int rg = 0; rg < 4; rg++) {
      float ivv = __shfl(qt ? inv1 : inv0, qd*4 + rg);
      int r = qt*16 + qd*4 + rg;
      bf16* cp = cat + crow0 + (size_t)r * D_ + ln;
#pragma unroll
      for (int nt = 0; nt < 4; nt++) cp[nt*16] = f2b(o[qt][nt][rg] * ivv);
    }
  }
}

// ---------------- LN1 apply (bf16 in/out), stats precomputed, bf16 gamma/beta --------
__global__ __launch_bounds__(256) void ln_b16_b16(const bf16* __restrict__ in,
    const float* __restrict__ stats, const bf16* __restrict__ gamma,
    const bf16* __restrict__ beta, bf16* __restrict__ out)
{
  const int b = blockIdx.x >> 4;
  const float invN = 1.f / (float)(S_*D_);
  const float m    = stats[b*2] * invN;
  const float var  = stats[b*2+1] * invN - m*m;
  const float rstd = rsqrtf(var + 1e-5f);
  size_t v = (size_t)b * 65536 + (blockIdx.x & 15) * 4096 + threadIdx.x;
#pragma unroll 4
  for (int it = 0; it < 16; it++, v += 256) {
    us4 xi = *(const us4*)((const unsigned short*)in + v*4);
    size_t e = (v * 4) & (S_*D_ - 1);
    us4 g4 = *(const us4*)((const unsigned short*)gamma + e);
    us4 b4 = *(const us4*)((const unsigned short*)beta + e);
    us4 o;
    o[0] = f2bu((bu2f(xi[0]) - m) * rstd * bu2f(g4[0]) + bu2f(b4[0]));
    o[1] = f2bu((bu2f(xi[1]) - m) * rstd * bu2f(g4[1]) + bu2f(b4[1]));
    o[2] = f2bu((bu2f(xi[2]) - m) * rstd * bu2f(g4[2]) + bu2f(b4[2]));
    o[3] = f2bu((bu2f(xi[3]) - m) * rstd * bu2f(g4[3]) + bu2f(b4[3]));
    *(us4*)((unsigned short*)out + v*4) = o;
  }
}

// ---------------- fused LN2+LN3: single pass yB -> out -------------------------------
// LN2 params (m2,r2) from extended stats {Sv,Svv}; LN3 params derived ALGEBRAICALLY:
//   Sy  = r2*(SGv - m2*CG) + CB
//   SSy = r2^2*(SG2v2 - 2*m2*SG2v + m2^2*CG2) + 2*r2*(SGBv - m2*CGB) + CB2
// where y2 = (v-m2)*r2*g + b; out = (y2-m3)*r3*g + b. Eliminates the y2 pass.
__global__ __launch_bounds__(256) void ln23_fused(const bf16* __restrict__ in,
    const float* __restrict__ st2x, const float* __restrict__ cst,
    const bf16* __restrict__ gamma, const bf16* __restrict__ beta,
    void* __restrict__ out, const int* __restrict__ flag)
{
  const bool f32 = (*flag != 0);
  const int b = blockIdx.x >> 4;
  const float invN = 1.f / (float)(S_*D_);
  const float Sv   = st2x[b*6+0], Svv  = st2x[b*6+1];
  const float SGv  = st2x[b*6+2], SG2v = st2x[b*6+3];
  const float SG2v2= st2x[b*6+4], SGBv = st2x[b*6+5];
  const float CG = cst[0], CG2 = cst[1], CGB = cst[2], CB = cst[3], CB2 = cst[4];
  const float m2 = Sv * invN;
  const float r2 = rsqrtf(Svv * invN - m2*m2 + 1e-5f);
  const float Sy  = r2 * (SGv - m2*CG) + CB;
  const float SSy = r2*r2 * (SG2v2 - 2.f*m2*SG2v + m2*m2*CG2)
                  + 2.f*r2 * (SGBv - m2*CGB) + CB2;
  const float m3 = Sy * invN;
  const float r3 = rsqrtf(SSy * invN - m3*m3 + 1e-5f);

  size_t v = (size_t)b * 65536 + (blockIdx.x & 15) * 4096 + threadIdx.x;
#pragma unroll 4
  for (int it = 0; it < 16; it++, v += 256) {
    us4 xi = *(const us4*)((const unsigned short*)in + v*4);
    size_t e = (v * 4) & (S_*D_ - 1);
    us4 g4 = *(const us4*)((const unsigned short*)gamma + e);
    us4 b4 = *(const us4*)((const unsigned short*)beta + e);
    float4 o;
    {
      float G = bu2f(g4[0]), B = bu2f(b4[0]);
      float y2 = (bu2f(xi[0]) - m2) * r2 * G + B;
      o.x = (y2 - m3) * r3 * G + B;
    }
    {
      float G = bu2f(g4[1]), B = bu2f(b4[1]);
      float y2 = (bu2f(xi[1]) - m2) * r2 * G + B;
      o.y = (y2 - m3) * r3 * G + B;
    }
    {
      float G = bu2f(g4[2]), B = bu2f(b4[2]);
      float y2 = (bu2f(xi[2]) - m2) * r2 * G + B;
      o.z = (y2 - m3) * r3 * G + B;
    }
    {
      float G = bu2f(g4[3]), B = bu2f(b4[3]);
      float y2 = (bu2f(xi[3]) - m2) * r2 * G + B;
      o.w = (y2 - m3) * r3 * G + B;
    }
    if (f32) ((float4*)out)[v] = o;
    else {
      us4 ob;
      ob[0] = f2bu(o.x); ob[1] = f2bu(o.y); ob[2] = f2bu(o.z); ob[3] = f2bu(o.w);
      *(us4*)((unsigned short*)out + v*4) = ob;
    }
  }
}

// ---------------- launch ----------------
extern "C" void kernel_launch(void* const* d_in, const int* in_sizes, int n_in,
                              void* d_out, int out_size, void* d_ws, size_t ws_size,
                              hipStream_t stream)
{
  char* p = (char*)d_ws;
  auto alloc_b = [&](size_t elems) { void* r = p; p += elems * 2; return (bf16*)r; };
  auto alloc_f = [&](size_t elems) {
    p = (char*)(((uintptr_t)p + 15) & ~(uintptr_t)15); void* r = p; p += elems * 4; return (float*)r;
  };

  bf16* xb   = alloc_b(MSD);            // x bf16
  bf16* qkv  = alloc_b(3 * MSD);        // [M][1536] natural
  bf16* catb = alloc_b(MSD);
  bf16* wqkv = alloc_b(3 * 512 * 512);
  bf16* wo   = alloc_b(512 * 512);
  bf16* w1p  = alloc_b((size_t)FFP * 512);
  bf16* w2p  = alloc_b((size_t)FFP * FFP);
  bf16* w3p  = alloc_b((size_t)512 * FFP);
  bf16* gm   = alloc_b((size_t)S_ * D_);   // gamma bf16
  bf16* bt   = alloc_b((size_t)S_ * D_);   // beta  bf16
  float* bqkv= alloc_f(3 * 512);
  float* bo  = alloc_f(512);
  float* b1p = alloc_f(FFP);
  float* b2p = alloc_f(FFP);
  float* b3  = alloc_f(512);
  float* stats = alloc_f(320);          // st1(64) | cst(16) | st2x(192) | pad
  int*   flag  = (int*)alloc_f(16);
  if ((size_t)(p - (char*)d_ws) > ws_size) return;

  // intermediates aliased into dead regions:
  bf16* y1b = qkv;                      // LN1 out [M][512]   (qkv dead after attn)
  bf16* f1  = qkv + MSD;                // [M][FFP]
  bf16* f2  = qkv + MSD + (size_t)M_ * FFP;
  bf16* yA  = qkv + 2 * MSD;            // out-proj + residual (bf16)
  bf16* yB  = catb;                     // FFN3 + residual     (catb dead after out-proj)
  float* st1  = stats;                  // LN1 stats, 2/batch
  float* cst  = stats + 64;             // gamma/beta consts: CG,CG2,CGB,CB,CB2
  float* st2x = stats + 80;             // extended LN23 stats, 6/batch

  detect_kernel<<<1, 256, 0, stream>>>((const unsigned short*)d_in[0], flag, stats);

  Segs sg;
  // {src, dst, srcRows, srcK, dstK, total}
  sg.s[0]  = { d_in[1],  wqkv,               512, 512, 512, 512*512 };
  sg.s[1]  = { d_in[3],  wqkv + 512*512,     512, 512, 512, 512*512 };
  sg.s[2]  = { d_in[5],  wqkv + 2*512*512,   512, 512, 512, 512*512 };
  sg.s[3]  = { d_in[7],  wo,                 512, 512, 512, 512*512 };
  sg.s[4]  = { d_in[9],  w1p,                FF_, 512, 512, FFP*512 };
  sg.s[5]  = { d_in[11], w2p,                FF_, FF_, FFP, FFP*FFP };
  sg.s[6]  = { d_in[13], w3p,                512, FF_, FFP, 512*FFP };
  sg.s[7]  = { d_in[2],  bqkv,               1, 512, 512, 512 };
  sg.s[8]  = { d_in[4],  bqkv + 512,         1, 512, 512, 512 };
  sg.s[9]  = { d_in[6],  bqkv + 1024,        1, 512, 512, 512 };
  sg.s[10] = { d_in[8],  bo,                 1, 512, 512, 512 };
  sg.s[11] = { d_in[10], b1p,                1, FF_, FFP, FFP };
  sg.s[12] = { d_in[12], b2p,                1, FF_, FFP, FFP };
  sg.s[13] = { d_in[14], b3,                 1, 512, 512, 512 };
  sg.s[14] = { d_in[15], gm,                 1, S_*D_, S_*D_, S_*D_ };
  sg.s[15] = { d_in[16], bt,                 1, S_*D_, S_*D_, S_*D_ };
  sg.isbf = 0xC07F;                     // weights + gamma/beta are bf16

  // fused front-end: x convert + seg convert + gamma/beta constants (one launch)
  cvt_fused<<<3136, 256, 0, stream>>>(d_in[0], xb, sg, flag, d_in[15], d_in[16], cst);

  dim3 blk(256);

  // fused QKV projection: plain GEMM, natural output [M][1536]
  gemm_mfma<0, 0, 128><<<dim3(M_/128, NQKV/128), blk, 0, stream>>>(
      xb, wqkv, bqkv, nullptr, qkv, M_, NQKV, 512, nullptr, nullptr, nullptr);

  attn_lds<<<B_*H_, 1024, 0, stream>>>(qkv, catb);

  // output projection + residual x -> bf16 yA, fused LN1 stats
  gemm_mfma<2, 1, 128><<<dim3(M_/128, 4), blk, 0, stream>>>(
      catb, wo, bo, xb, yA, M_, 512, 512, st1, nullptr, nullptr);

  ln_b16_b16<<<512, blk, 0, stream>>>(yA, st1, gm, bt, y1b);

  // FFN (padded to 256). BM=64 for FFN1/2: grid 512 blocks = 2/CU (was 1/CU).
  gemm_mfma<1, 0, 64><<<dim3(M_/64, 2), blk, 0, stream>>>(
      y1b, w1p, b1p, nullptr, f1, M_, FFP, 512, nullptr, nullptr, nullptr);
  gemm_mfma<1, 0, 64><<<dim3(M_/64, 2), blk, 0, stream>>>(
      f1, w2p, b2p, nullptr, f2, M_, FFP, FFP, nullptr, nullptr, nullptr);
  // FFN3 + residual -> yB, with EXTENDED stats for the LN2+LN3 fusion
  gemm_mfma<2, 2, 128><<<dim3(M_/128, 4), blk, 0, stream>>>(
      f2, w3p, b3, y1b, yB, M_, 512, FFP, st2x, gm, bt);

  // fused LN2-apply + LN3 (stats derived algebraically) -> out, single pass
  ln23_fused<<<512, blk, 0, stream>>>(yB, st2x, cst, gm, bt, d_out, flag);
}